// Round 3
// baseline (7389.002 us; speedup 1.0000x reference)
//
#include <hip/hip_runtime.h>

#define EPSV 1e-5f

__device__ __forceinline__ float sigmoidf_(float x) {
  return 1.f / (1.f + __expf(-x));
}
__device__ __forceinline__ unsigned short f2bf(float f) {
  unsigned int u = __float_as_uint(f);
  u += 0x7fffu + ((u >> 16) & 1u);
  return (unsigned short)(u >> 16);
}
__device__ __forceinline__ float bfu(unsigned short h) {
  union { unsigned int u; float f; } t; t.u = ((unsigned int)h) << 16; return t.f;
}

// ---------------------------------------------------------------------------
// W_comb[i][m][k] = sum_j fusion_W[p][m][d*64+j] * out_W[i][j][k]
// ---------------------------------------------------------------------------
__global__ __launch_bounds__(256) void precomp_wc(
    const float* __restrict__ fW,   // (2,64,128)
    const float* __restrict__ oW,   // (4,64,128)
    float* __restrict__ Wc)         // (4,64,128)
{
  const int bi = blockIdx.x;
  const int i = bi >> 3, mg = bi & 7;
  const int m = (mg << 3) + (threadIdx.x >> 5);
  const int k0 = (threadIdx.x & 31) << 2;
  const int p = i >> 1, d = i & 1;
  const float* fr = fW + p * 8192 + m * 128 + d * 64;
  const float* orow = oW + i * 8192 + k0;
  float a0 = 0.f, a1 = 0.f, a2 = 0.f, a3 = 0.f;
  for (int j = 0; j < 64; ++j) {
    const float f = fr[j];
    const float4 o4 = *(const float4*)(orow + j * 128);
    a0 += f * o4.x; a1 += f * o4.y; a2 += f * o4.z; a3 += f * o4.w;
  }
  float* out = Wc + i * 8192 + m * 128 + k0;
  out[0] = a0; out[1] = a1; out[2] = a2; out[3] = a3;
}

// ---------------------------------------------------------------------------
// One block = one (sequence, direction). 1024 blocks/phase. CH=8 tokens.
// LDS 20.6 KB -> 4 resident blocks/CU (16 waves/CU). No atomics: writes
// compact bf16 y[dir][seq][pos][64].
// ---------------------------------------------------------------------------
__global__ __launch_bounds__(256, 4) void mamba_dir(
    const float* __restrict__ xin,   // canonical x (4,64,128,128) f32
    const float* __restrict__ x1,    // phase1 input [b][f][t][c] f32
    unsigned short* __restrict__ ybuf, // bf16 [dir][seq][pos][64]
    const float* __restrict__ WpA, const float* __restrict__ cwA,
    const float* __restrict__ cbA, const float* __restrict__ dtbA,
    const float* __restrict__ AlA, const float* __restrict__ DpA,
    const float* __restrict__ nwA, const float* __restrict__ lnwA,
    const float* __restrict__ lnbA, const float* __restrict__ WcA,
    int phase)
{
  __shared__ float sZ[8 * 388];   // z(0-127)|xBC(128-383)|dtraw(384-385); y/g overlay 128-255
  __shared__ float sX[8][256];    // conv+silu out; u aliased in cols 0-63 pre-conv

  const int tid = threadIdx.x;
  const int blk = blockIdx.x;
  const int seq = blk >> 1, dir = blk & 1;
  const int b = seq >> 7, q = seq & 127;
  const int ip = (phase << 1) + dir;
  const float* Wp = WpA + (size_t)ip * 24704;
  const float* Wc = WcA + (size_t)ip * 8192;
  const float dtb0 = dtbA[ip * 2], dtb1 = dtbA[ip * 2 + 1];
  const float nA0 = -__expf(AlA[ip * 2]), nA1 = -__expf(AlA[ip * 2 + 1]);
  const float Dp0 = DpA[ip * 2], Dp1 = DpA[ip * 2 + 1];
  // conv params: this thread owns channel c = tid for the whole kernel
  const float4 cw4 = *(const float4*)(cwA + ip * 1024 + (tid << 2));
  const float cbias = cbA[ip * 256 + tid];
  float ch0 = 0.f, ch1 = 0.f, ch2 = 0.f;   // conv history (registers)
  float S[32];                              // scan state (registers)
  #pragma unroll
  for (int i = 0; i < 32; ++i) S[i] = 0.f;

  const size_t sb = phase ? ((size_t)b * 1048576 + (size_t)q * 8192)
                          : ((size_t)b * 1048576 + (size_t)q * 128);
  const float* src = phase ? x1 : xin;

  for (int ck = 0; ck < 16; ++ck) {
    // ---- 1. load 8 pos x 64 ch into sX (u region) ----
    if (phase) {
      const int pos = tid >> 5, cl = (tid & 31) << 1;
      const int st = (ck << 3) + pos, rp = dir ? (127 - st) : st;
      const float2 v = *(const float2*)(src + sb + (size_t)rp * 64 + cl);
      sX[pos][cl] = v.x; sX[pos][cl + 1] = v.y;
    } else {
      const int pos = tid & 7, c0 = (tid >> 3) << 1;
      const int st = (ck << 3) + pos, rp = dir ? (127 - st) : st;
      const float* p = src + sb + rp;
      sX[pos][c0]     = p[(size_t)c0 * 16384];
      sX[pos][c0 + 1] = p[(size_t)(c0 + 1) * 16384];
    }
    __syncthreads();
    // ---- 2. layernorm (in place) ----
    {
      const int pos = tid >> 5, cl = (tid & 31) << 1;
      const float v0 = sX[pos][cl], v1 = sX[pos][cl + 1];
      float sm = v0 + v1, s2 = v0 * v0 + v1 * v1;
      sm += __shfl_xor(sm, 1);  s2 += __shfl_xor(s2, 1);
      sm += __shfl_xor(sm, 2);  s2 += __shfl_xor(s2, 2);
      sm += __shfl_xor(sm, 4);  s2 += __shfl_xor(s2, 4);
      sm += __shfl_xor(sm, 8);  s2 += __shfl_xor(s2, 8);
      sm += __shfl_xor(sm, 16); s2 += __shfl_xor(s2, 16);
      const float mean = sm * (1.f / 64.f);
      const float inv = rsqrtf(s2 * (1.f / 64.f) - mean * mean + EPSV);
      const int lb = (phase << 6) + cl;
      sX[pos][cl]     = (v0 - mean) * inv * lnwA[lb] + lnbA[lb];
      sX[pos][cl + 1] = (v1 - mean) * inv * lnwA[lb + 1] + lnbA[lb + 1];
    }
    __syncthreads();
    // ---- 3. in_proj: sZ[lt][o] = u[lt] . Wp[o]  (two K-halves, w in 32 regs) ----
    for (int r = 0; r < 2; ++r) {
      const int o = tid + (r << 8);
      if (o < 386) {
        const float4* wp4 = (const float4*)(Wp + ((size_t)o << 6));
        float acc[8];
        #pragma unroll
        for (int lt = 0; lt < 8; ++lt) acc[lt] = 0.f;
        #pragma unroll
        for (int h = 0; h < 2; ++h) {
          float4 w[8];
          #pragma unroll
          for (int i = 0; i < 8; ++i) w[i] = wp4[h * 8 + i];
          #pragma unroll
          for (int lt = 0; lt < 8; ++lt) {
            const float4* ur = (const float4*)(&sX[lt][h << 5]);
            float a = acc[lt];
            #pragma unroll
            for (int i = 0; i < 8; ++i) {
              const float4 u4 = ur[i];
              a += w[i].x * u4.x + w[i].y * u4.y + w[i].z * u4.z + w[i].w * u4.w;
            }
            acc[lt] = a;
          }
        }
        #pragma unroll
        for (int lt = 0; lt < 8; ++lt) sZ[lt * 388 + o] = acc[lt];
      }
    }
    __syncthreads();
    // ---- 4. conv(4,causal)+silu; history in registers ----
    {
      float a0 = ch0, a1 = ch1, a2 = ch2;
      #pragma unroll
      for (int lt = 0; lt < 8; ++lt) {
        const float a3 = sZ[lt * 388 + 128 + tid];
        const float acc = cbias + a0 * cw4.x + a1 * cw4.y + a2 * cw4.z + a3 * cw4.w;
        sX[lt][tid] = acc * sigmoidf_(acc);
        a0 = a1; a1 = a2; a2 = a3;
      }
      ch0 = a0; ch1 = a1; ch2 = a2;
    }
    __syncthreads();
    // ---- 5. selective scan: 128 rows x 2 halves; dt/dA recomputed in place ----
    {
      const int row = tid >> 1, half = tid & 1, hh = row >> 6;
      const int boff = 128 + (half << 5);
      const float dtbh = hh ? dtb1 : dtb0, nAh = hh ? nA1 : nA0;
      #pragma unroll
      for (int lt = 0; lt < 8; ++lt) {
        const float rawv = sZ[lt * 388 + 384 + hh] + dtbh;
        const float dtv = (rawv > 20.f) ? rawv : log1pf(__expf(rawv));
        const float dA = __expf(dtv * nAh);
        const float dtx = dtv * sX[lt][row];
        const float4* Bp = (const float4*)(&sX[lt][boff]);
        const float4* Cp = (const float4*)(&sX[lt][boff + 64]);
        float yp = 0.f;
        #pragma unroll
        for (int i = 0; i < 8; ++i) {
          const float4 Bv = Bp[i], Cv = Cp[i];
          S[i * 4 + 0] = S[i * 4 + 0] * dA + dtx * Bv.x; yp += S[i * 4 + 0] * Cv.x;
          S[i * 4 + 1] = S[i * 4 + 1] * dA + dtx * Bv.y; yp += S[i * 4 + 1] * Cv.y;
          S[i * 4 + 2] = S[i * 4 + 2] * dA + dtx * Bv.z; yp += S[i * 4 + 2] * Cv.z;
          S[i * 4 + 3] = S[i * 4 + 3] * dA + dtx * Bv.w; yp += S[i * 4 + 3] * Cv.w;
        }
        yp += __shfl_xor(yp, 1);
        if (!half) sZ[lt * 388 + 128 + row] = yp;   // y overlays dead xBC region
      }
    }
    __syncthreads();
    // ---- 6. gate with silu(z) + rmsnorm ----
    {
      const int lt = tid >> 5, c0 = (tid & 31) << 2;
      const float4 yv = *(const float4*)(&sZ[lt * 388 + 128 + c0]);
      const float4 zv = *(const float4*)(&sZ[lt * 388 + c0]);
      const float4 xv = *(const float4*)(&sX[lt][c0]);
      const float dp = (c0 & 64) ? Dp1 : Dp0;
      const float g0 = (yv.x + dp * xv.x) * (zv.x * sigmoidf_(zv.x));
      const float g1 = (yv.y + dp * xv.y) * (zv.y * sigmoidf_(zv.y));
      const float g2 = (yv.z + dp * xv.z) * (zv.z * sigmoidf_(zv.z));
      const float g3 = (yv.w + dp * xv.w) * (zv.w * sigmoidf_(zv.w));
      float ssq = g0 * g0 + g1 * g1 + g2 * g2 + g3 * g3;
      ssq += __shfl_xor(ssq, 1);
      ssq += __shfl_xor(ssq, 2);
      ssq += __shfl_xor(ssq, 4);
      ssq += __shfl_xor(ssq, 8);
      ssq += __shfl_xor(ssq, 16);
      const float sc = rsqrtf(ssq * (1.f / 128.f) + EPSV);
      const float4 nw4 = *(const float4*)(nwA + ip * 128 + c0);
      float4 gv;
      gv.x = g0 * sc * nw4.x; gv.y = g1 * sc * nw4.y;
      gv.z = g2 * sc * nw4.z; gv.w = g3 * sc * nw4.w;
      *(float4*)(&sZ[lt * 388 + 128 + c0]) = gv;
    }
    __syncthreads();
    // ---- 7. fused out_proj+fusion matmul -> compact bf16 store ----
    {
      const int lt = tid >> 5, mb = tid & 31;
      const float4* gy = (const float4*)(&sZ[lt * 388 + 128]);
      const float4* wa = (const float4*)(Wc + ((size_t)mb << 7));
      const float4* wb = (const float4*)(Wc + ((size_t)(mb + 32) << 7));
      float acc0 = 0.f, acc1 = 0.f;
      #pragma unroll
      for (int i = 0; i < 32; ++i) {
        const float4 gv = gy[i], av = wa[i], bv = wb[i];
        acc0 += av.x * gv.x + av.y * gv.y + av.z * gv.z + av.w * gv.w;
        acc1 += bv.x * gv.x + bv.y * gv.y + bv.z * gv.z + bv.w * gv.w;
      }
      const int st = (ck << 3) + lt, rp = dir ? (127 - st) : st;
      unsigned short* yo = ybuf + (((size_t)(dir * 512 + seq) * 128 + rp) << 6);
      yo[mb] = f2bf(acc0);
      yo[mb + 32] = f2bf(acc1);
    }
    __syncthreads();
  }
}

// ---------------------------------------------------------------------------
// combine0: x1[b][f][t][c] = x[b][c][t][f] + yf + yb + fb0[c]   (all coalesced)
// ---------------------------------------------------------------------------
__global__ __launch_bounds__(256) void combine0(
    const float* __restrict__ x, const unsigned short* __restrict__ ybuf,
    const float* __restrict__ fb, float* __restrict__ x1)
{
  __shared__ float T[64 * 132];
  const int tid = threadIdx.x, blk = blockIdx.x;
  const int b = blk >> 7, t = blk & 127;
  {
    const int c = tid >> 2, f0 = (tid & 3) << 5;
    const float* xp = x + (((size_t)(b * 64 + c) * 128 + t) << 7) + f0;
    float* tp = &T[c * 132 + f0];
    #pragma unroll
    for (int j = 0; j < 8; ++j)
      *(float4*)(tp + (j << 2)) = *(const float4*)(xp + (j << 2));
  }
  __syncthreads();
  {
    const int f = tid >> 1, cb = (tid & 1) << 5;
    const size_t s0 = (size_t)b * 128 + t;
    const unsigned short* yf = ybuf + ((s0 * 128 + f) << 6) + cb;
    const unsigned short* yb = ybuf + (((s0 + 512) * 128 + f) << 6) + cb;
    float* op = x1 + (((size_t)(b * 128 + f) * 128 + t) << 6) + cb;
    #pragma unroll
    for (int j = 0; j < 32; j += 4) {
      float4 v;
      v.x = T[(cb + j + 0) * 132 + f] + bfu(yf[j + 0]) + bfu(yb[j + 0]) + fb[cb + j + 0];
      v.y = T[(cb + j + 1) * 132 + f] + bfu(yf[j + 1]) + bfu(yb[j + 1]) + fb[cb + j + 1];
      v.z = T[(cb + j + 2) * 132 + f] + bfu(yf[j + 2]) + bfu(yb[j + 2]) + fb[cb + j + 2];
      v.w = T[(cb + j + 3) * 132 + f] + bfu(yf[j + 3]) + bfu(yb[j + 3]) + fb[cb + j + 3];
      *(float4*)(op + j) = v;
    }
  }
}

// ---------------------------------------------------------------------------
// combine1: out[b][c][t][f] = x1[b][f][t][c] + yf + yb + fb1[c]  (all coalesced)
// ---------------------------------------------------------------------------
__global__ __launch_bounds__(256) void combine1(
    const float* __restrict__ x1, const unsigned short* __restrict__ ybuf,
    const float* __restrict__ fb, float* __restrict__ out)
{
  __shared__ float T[128 * 68];
  const int tid = threadIdx.x, blk = blockIdx.x;
  const int b = blk >> 7, t = blk & 127;
  {
    const int f = tid >> 1, cb = (tid & 1) << 5;
    const size_t s1 = (size_t)b * 128 + f;
    const float* xp = x1 + ((s1 * 128 + t) << 6) + cb;
    const unsigned short* yf = ybuf + ((s1 * 128 + t) << 6) + cb;
    const unsigned short* yb = ybuf + (((s1 + 512) * 128 + t) << 6) + cb;
    float* tp = &T[f * 68 + cb];
    #pragma unroll
    for (int j = 0; j < 32; ++j)
      tp[j] = xp[j] + bfu(yf[j]) + bfu(yb[j]) + fb[cb + j];
  }
  __syncthreads();
  {
    const int c = tid >> 2, f0 = (tid & 3) << 5;
    float* op = out + (((size_t)(b * 64 + c) * 128 + t) << 7) + f0;
    #pragma unroll
    for (int j = 0; j < 32; j += 4) {
      float4 v;
      v.x = T[(f0 + j + 0) * 68 + c];
      v.y = T[(f0 + j + 1) * 68 + c];
      v.z = T[(f0 + j + 2) * 68 + c];
      v.w = T[(f0 + j + 3) * 68 + c];
      *(float4*)(op + j) = v;
    }
  }
}

extern "C" void kernel_launch(void* const* d_in, const int* in_sizes, int n_in,
                              void* d_out, int out_size, void* d_ws, size_t ws_size,
                              hipStream_t stream) {
  const float* x   = (const float*)d_in[0];
  const float* Wp  = (const float*)d_in[1];
  const float* cw  = (const float*)d_in[2];
  const float* cb  = (const float*)d_in[3];
  const float* dtb = (const float*)d_in[4];
  const float* Al  = (const float*)d_in[5];
  const float* Dp  = (const float*)d_in[6];
  const float* nw  = (const float*)d_in[7];
  const float* oW  = (const float*)d_in[8];
  const float* fW  = (const float*)d_in[9];
  const float* fb  = (const float*)d_in[10];
  const float* lnw = (const float*)d_in[11];
  const float* lnb = (const float*)d_in[12];

  float* ws = (float*)d_ws;
  float* Wc = ws;                              // 32768 f32
  float* x1 = ws + 32768;                      // 4194304 f32
  unsigned short* y = (unsigned short*)(ws + 32768 + 4194304); // 8388608 bf16

  precomp_wc<<<32, 256, 0, stream>>>(fW, oW, Wc);
  mamba_dir<<<1024, 256, 0, stream>>>(x, x1, y, Wp, cw, cb, dtb, Al, Dp,
                                      nw, lnw, lnb, Wc, 0);
  combine0<<<512, 256, 0, stream>>>(x, y, fb, x1);
  mamba_dir<<<1024, 256, 0, stream>>>(x, x1, y, Wp, cw, cb, dtb, Al, Dp,
                                      nw, lnw, lnb, Wc, 1);
  combine1<<<512, 256, 0, stream>>>(x1, y, fb + 64, (float*)d_out);
}

// Round 4
// 6537.018 us; speedup vs baseline: 1.1303x; 1.1303x over previous
//
#include <hip/hip_runtime.h>

#define EPSV 1e-5f

__device__ __forceinline__ float sigmoidf_(float x) {
  return 1.f / (1.f + __expf(-x));
}
__device__ __forceinline__ unsigned short f2bf(float f) {
  unsigned int u = __float_as_uint(f);
  u += 0x7fffu + ((u >> 16) & 1u);
  return (unsigned short)(u >> 16);
}
__device__ __forceinline__ float bfu(unsigned short h) {
  union { unsigned int u; float f; } t; t.u = ((unsigned int)h) << 16; return t.f;
}

// ---------------------------------------------------------------------------
// W_comb[i][m][k] = sum_j fusion_W[p][m][d*64+j] * out_W[i][j][k]
// ---------------------------------------------------------------------------
__global__ __launch_bounds__(256) void precomp_wc(
    const float* __restrict__ fW,   // (2,64,128)
    const float* __restrict__ oW,   // (4,64,128)
    float* __restrict__ Wc)         // (4,64,128)
{
  const int bi = blockIdx.x;
  const int i = bi >> 3, mg = bi & 7;
  const int m = (mg << 3) + (threadIdx.x >> 5);
  const int k0 = (threadIdx.x & 31) << 2;
  const int p = i >> 1, d = i & 1;
  const float* fr = fW + p * 8192 + m * 128 + d * 64;
  const float* orow = oW + i * 8192 + k0;
  float a0 = 0.f, a1 = 0.f, a2 = 0.f, a3 = 0.f;
  for (int j = 0; j < 64; ++j) {
    const float f = fr[j];
    const float4 o4 = *(const float4*)(orow + j * 128);
    a0 += f * o4.x; a1 += f * o4.y; a2 += f * o4.z; a3 += f * o4.w;
  }
  float* out = Wc + i * 8192 + m * 128 + k0;
  out[0] = a0; out[1] = a1; out[2] = a2; out[3] = a3;
}

// ---------------------------------------------------------------------------
// One block = one (sequence, direction). 1024 blocks/phase. CH=8 tokens.
// LDS 20.6 KB. launch_bounds(256,2): round-2-proven VGPR=128 shape, NO SPILLS
// (round 3's (256,4) bound forced 64 VGPRs -> 11 GB scratch traffic).
// ---------------------------------------------------------------------------
__global__ __launch_bounds__(256, 2) void mamba_dir(
    const float* __restrict__ xin,   // canonical x (4,64,128,128) f32
    const float* __restrict__ x1,    // phase1 input [b][f][t][c] f32
    unsigned short* __restrict__ ybuf, // bf16 [dir][seq][pos][64]
    const float* __restrict__ WpA, const float* __restrict__ cwA,
    const float* __restrict__ cbA, const float* __restrict__ dtbA,
    const float* __restrict__ AlA, const float* __restrict__ DpA,
    const float* __restrict__ nwA, const float* __restrict__ lnwA,
    const float* __restrict__ lnbA, const float* __restrict__ WcA,
    int phase)
{
  __shared__ float sZ[8 * 388];   // z(0-127)|xBC(128-383)|dtraw(384-385); y/g overlay 128-255
  __shared__ float sX[8][256];    // conv+silu out; u aliased in cols 0-63 pre-conv

  const int tid = threadIdx.x;
  const int blk = blockIdx.x;
  const int seq = blk >> 1, dir = blk & 1;
  const int b = seq >> 7, q = seq & 127;
  const int ip = (phase << 1) + dir;
  const float* Wp = WpA + (size_t)ip * 24704;
  const float* Wc = WcA + (size_t)ip * 8192;
  const float dtb0 = dtbA[ip * 2], dtb1 = dtbA[ip * 2 + 1];
  const float nA0 = -__expf(AlA[ip * 2]), nA1 = -__expf(AlA[ip * 2 + 1]);
  const float Dp0 = DpA[ip * 2], Dp1 = DpA[ip * 2 + 1];
  // conv params: this thread owns channel c = tid for the whole kernel
  const float4 cw4 = *(const float4*)(cwA + ip * 1024 + (tid << 2));
  const float cbias = cbA[ip * 256 + tid];
  float ch0 = 0.f, ch1 = 0.f, ch2 = 0.f;   // conv history (registers)
  float S[32];                              // scan state (registers)
  #pragma unroll
  for (int i = 0; i < 32; ++i) S[i] = 0.f;

  const size_t sb = phase ? ((size_t)b * 1048576 + (size_t)q * 8192)
                          : ((size_t)b * 1048576 + (size_t)q * 128);
  const float* src = phase ? x1 : xin;

  for (int ck = 0; ck < 16; ++ck) {
    // ---- 1. load 8 pos x 64 ch into sX (u region) ----
    if (phase) {
      const int pos = tid >> 5, cl = (tid & 31) << 1;
      const int st = (ck << 3) + pos, rp = dir ? (127 - st) : st;
      const float2 v = *(const float2*)(src + sb + (size_t)rp * 64 + cl);
      sX[pos][cl] = v.x; sX[pos][cl + 1] = v.y;
    } else {
      const int pos = tid & 7, c0 = (tid >> 3) << 1;
      const int st = (ck << 3) + pos, rp = dir ? (127 - st) : st;
      const float* p = src + sb + rp;
      sX[pos][c0]     = p[(size_t)c0 * 16384];
      sX[pos][c0 + 1] = p[(size_t)(c0 + 1) * 16384];
    }
    __syncthreads();
    // ---- 2. layernorm (in place) ----
    {
      const int pos = tid >> 5, cl = (tid & 31) << 1;
      const float v0 = sX[pos][cl], v1 = sX[pos][cl + 1];
      float sm = v0 + v1, s2 = v0 * v0 + v1 * v1;
      sm += __shfl_xor(sm, 1);  s2 += __shfl_xor(s2, 1);
      sm += __shfl_xor(sm, 2);  s2 += __shfl_xor(s2, 2);
      sm += __shfl_xor(sm, 4);  s2 += __shfl_xor(s2, 4);
      sm += __shfl_xor(sm, 8);  s2 += __shfl_xor(s2, 8);
      sm += __shfl_xor(sm, 16); s2 += __shfl_xor(s2, 16);
      const float mean = sm * (1.f / 64.f);
      const float inv = rsqrtf(s2 * (1.f / 64.f) - mean * mean + EPSV);
      const int lb = (phase << 6) + cl;
      sX[pos][cl]     = (v0 - mean) * inv * lnwA[lb] + lnbA[lb];
      sX[pos][cl + 1] = (v1 - mean) * inv * lnwA[lb + 1] + lnbA[lb + 1];
    }
    __syncthreads();
    // ---- 3. in_proj (round-2 proven register shape: w[64], scalar acc) ----
    for (int o = tid; o < 386; o += 256) {
      const float4* wp4 = (const float4*)(Wp + ((size_t)o << 6));
      float w[64];
      #pragma unroll
      for (int i = 0; i < 16; ++i) {
        const float4 a = wp4[i];
        w[i * 4 + 0] = a.x; w[i * 4 + 1] = a.y;
        w[i * 4 + 2] = a.z; w[i * 4 + 3] = a.w;
      }
      for (int lt = 0; lt < 8; ++lt) {
        const float4* ur = (const float4*)(&sX[lt][0]);
        float acc = 0.f;
        #pragma unroll
        for (int i = 0; i < 16; ++i) {
          const float4 uv = ur[i];
          acc += w[i * 4 + 0] * uv.x + w[i * 4 + 1] * uv.y +
                 w[i * 4 + 2] * uv.z + w[i * 4 + 3] * uv.w;
        }
        sZ[lt * 388 + o] = acc;
      }
    }
    __syncthreads();
    // ---- 4. conv(4,causal)+silu; history in registers ----
    {
      float a0 = ch0, a1 = ch1, a2 = ch2;
      #pragma unroll
      for (int lt = 0; lt < 8; ++lt) {
        const float a3 = sZ[lt * 388 + 128 + tid];
        const float acc = cbias + a0 * cw4.x + a1 * cw4.y + a2 * cw4.z + a3 * cw4.w;
        sX[lt][tid] = acc * sigmoidf_(acc);
        a0 = a1; a1 = a2; a2 = a3;
      }
      ch0 = a0; ch1 = a1; ch2 = a2;
    }
    __syncthreads();
    // ---- 5. selective scan: 128 rows x 2 halves; dt/dA recomputed in place ----
    {
      const int row = tid >> 1, half = tid & 1, hh = row >> 6;
      const int boff = 128 + (half << 5);
      const float dtbh = hh ? dtb1 : dtb0, nAh = hh ? nA1 : nA0;
      #pragma unroll
      for (int lt = 0; lt < 8; ++lt) {
        const float rawv = sZ[lt * 388 + 384 + hh] + dtbh;
        const float dtv = (rawv > 20.f) ? rawv : log1pf(__expf(rawv));
        const float dA = __expf(dtv * nAh);
        const float dtx = dtv * sX[lt][row];
        const float4* Bp = (const float4*)(&sX[lt][boff]);
        const float4* Cp = (const float4*)(&sX[lt][boff + 64]);
        float yp = 0.f;
        #pragma unroll
        for (int i = 0; i < 8; ++i) {
          const float4 Bv = Bp[i], Cv = Cp[i];
          S[i * 4 + 0] = S[i * 4 + 0] * dA + dtx * Bv.x; yp += S[i * 4 + 0] * Cv.x;
          S[i * 4 + 1] = S[i * 4 + 1] * dA + dtx * Bv.y; yp += S[i * 4 + 1] * Cv.y;
          S[i * 4 + 2] = S[i * 4 + 2] * dA + dtx * Bv.z; yp += S[i * 4 + 2] * Cv.z;
          S[i * 4 + 3] = S[i * 4 + 3] * dA + dtx * Bv.w; yp += S[i * 4 + 3] * Cv.w;
        }
        yp += __shfl_xor(yp, 1);
        if (!half) sZ[lt * 388 + 128 + row] = yp;   // y overlays dead xBC region
      }
    }
    __syncthreads();
    // ---- 6. gate with silu(z) + rmsnorm ----
    {
      const int lt = tid >> 5, c0 = (tid & 31) << 2;
      const float4 yv = *(const float4*)(&sZ[lt * 388 + 128 + c0]);
      const float4 zv = *(const float4*)(&sZ[lt * 388 + c0]);
      const float4 xv = *(const float4*)(&sX[lt][c0]);
      const float dp = (c0 & 64) ? Dp1 : Dp0;
      const float g0 = (yv.x + dp * xv.x) * (zv.x * sigmoidf_(zv.x));
      const float g1 = (yv.y + dp * xv.y) * (zv.y * sigmoidf_(zv.y));
      const float g2 = (yv.z + dp * xv.z) * (zv.z * sigmoidf_(zv.z));
      const float g3 = (yv.w + dp * xv.w) * (zv.w * sigmoidf_(zv.w));
      float ssq = g0 * g0 + g1 * g1 + g2 * g2 + g3 * g3;
      ssq += __shfl_xor(ssq, 1);
      ssq += __shfl_xor(ssq, 2);
      ssq += __shfl_xor(ssq, 4);
      ssq += __shfl_xor(ssq, 8);
      ssq += __shfl_xor(ssq, 16);
      const float sc = rsqrtf(ssq * (1.f / 128.f) + EPSV);
      const float4 nw4 = *(const float4*)(nwA + ip * 128 + c0);
      float4 gv;
      gv.x = g0 * sc * nw4.x; gv.y = g1 * sc * nw4.y;
      gv.z = g2 * sc * nw4.z; gv.w = g3 * sc * nw4.w;
      *(float4*)(&sZ[lt * 388 + 128 + c0]) = gv;
    }
    __syncthreads();
    // ---- 7. fused out_proj+fusion matmul -> compact bf16 store ----
    {
      const int lt = tid >> 5, mb = tid & 31;
      const float4* gy = (const float4*)(&sZ[lt * 388 + 128]);
      const float4* wa = (const float4*)(Wc + ((size_t)mb << 7));
      const float4* wb = (const float4*)(Wc + ((size_t)(mb + 32) << 7));
      float acc0 = 0.f, acc1 = 0.f;
      #pragma unroll
      for (int i = 0; i < 32; ++i) {
        const float4 gv = gy[i], av = wa[i], bv = wb[i];
        acc0 += av.x * gv.x + av.y * gv.y + av.z * gv.z + av.w * gv.w;
        acc1 += bv.x * gv.x + bv.y * gv.y + bv.z * gv.z + bv.w * gv.w;
      }
      const int st = (ck << 3) + lt, rp = dir ? (127 - st) : st;
      unsigned short* yo = ybuf + (((size_t)(dir * 512 + seq) * 128 + rp) << 6);
      yo[mb] = f2bf(acc0);
      yo[mb + 32] = f2bf(acc1);
    }
    __syncthreads();
  }
}

// ---------------------------------------------------------------------------
// combine0: x1[b][f][t][c] = x[b][c][t][f] + yf + yb + fb0[c]   (all coalesced)
// ---------------------------------------------------------------------------
__global__ __launch_bounds__(256) void combine0(
    const float* __restrict__ x, const unsigned short* __restrict__ ybuf,
    const float* __restrict__ fb, float* __restrict__ x1)
{
  __shared__ float T[64 * 132];
  const int tid = threadIdx.x, blk = blockIdx.x;
  const int b = blk >> 7, t = blk & 127;
  {
    const int c = tid >> 2, f0 = (tid & 3) << 5;
    const float* xp = x + (((size_t)(b * 64 + c) * 128 + t) << 7) + f0;
    float* tp = &T[c * 132 + f0];
    #pragma unroll
    for (int j = 0; j < 8; ++j)
      *(float4*)(tp + (j << 2)) = *(const float4*)(xp + (j << 2));
  }
  __syncthreads();
  {
    const int f = tid >> 1, cb = (tid & 1) << 5;
    const size_t s0 = (size_t)b * 128 + t;
    const unsigned short* yf = ybuf + ((s0 * 128 + f) << 6) + cb;
    const unsigned short* yb = ybuf + (((s0 + 512) * 128 + f) << 6) + cb;
    float* op = x1 + (((size_t)(b * 128 + f) * 128 + t) << 6) + cb;
    #pragma unroll
    for (int j = 0; j < 32; j += 4) {
      float4 v;
      v.x = T[(cb + j + 0) * 132 + f] + bfu(yf[j + 0]) + bfu(yb[j + 0]) + fb[cb + j + 0];
      v.y = T[(cb + j + 1) * 132 + f] + bfu(yf[j + 1]) + bfu(yb[j + 1]) + fb[cb + j + 1];
      v.z = T[(cb + j + 2) * 132 + f] + bfu(yf[j + 2]) + bfu(yb[j + 2]) + fb[cb + j + 2];
      v.w = T[(cb + j + 3) * 132 + f] + bfu(yf[j + 3]) + bfu(yb[j + 3]) + fb[cb + j + 3];
      *(float4*)(op + j) = v;
    }
  }
}

// ---------------------------------------------------------------------------
// combine1: out[b][c][t][f] = x1[b][f][t][c] + yf + yb + fb1[c]  (all coalesced)
// ---------------------------------------------------------------------------
__global__ __launch_bounds__(256) void combine1(
    const float* __restrict__ x1, const unsigned short* __restrict__ ybuf,
    const float* __restrict__ fb, float* __restrict__ out)
{
  __shared__ float T[128 * 68];
  const int tid = threadIdx.x, blk = blockIdx.x;
  const int b = blk >> 7, t = blk & 127;
  {
    const int f = tid >> 1, cb = (tid & 1) << 5;
    const size_t s1 = (size_t)b * 128 + f;
    const float* xp = x1 + ((s1 * 128 + t) << 6) + cb;
    const unsigned short* yf = ybuf + ((s1 * 128 + t) << 6) + cb;
    const unsigned short* yb = ybuf + (((s1 + 512) * 128 + t) << 6) + cb;
    float* tp = &T[f * 68 + cb];
    #pragma unroll
    for (int j = 0; j < 32; ++j)
      tp[j] = xp[j] + bfu(yf[j]) + bfu(yb[j]) + fb[cb + j];
  }
  __syncthreads();
  {
    const int c = tid >> 2, f0 = (tid & 3) << 5;
    float* op = out + (((size_t)(b * 64 + c) * 128 + t) << 7) + f0;
    #pragma unroll
    for (int j = 0; j < 32; j += 4) {
      float4 v;
      v.x = T[(f0 + j + 0) * 68 + c];
      v.y = T[(f0 + j + 1) * 68 + c];
      v.z = T[(f0 + j + 2) * 68 + c];
      v.w = T[(f0 + j + 3) * 68 + c];
      *(float4*)(op + j) = v;
    }
  }
}

extern "C" void kernel_launch(void* const* d_in, const int* in_sizes, int n_in,
                              void* d_out, int out_size, void* d_ws, size_t ws_size,
                              hipStream_t stream) {
  const float* x   = (const float*)d_in[0];
  const float* Wp  = (const float*)d_in[1];
  const float* cw  = (const float*)d_in[2];
  const float* cb  = (const float*)d_in[3];
  const float* dtb = (const float*)d_in[4];
  const float* Al  = (const float*)d_in[5];
  const float* Dp  = (const float*)d_in[6];
  const float* nw  = (const float*)d_in[7];
  const float* oW  = (const float*)d_in[8];
  const float* fW  = (const float*)d_in[9];
  const float* fb  = (const float*)d_in[10];
  const float* lnw = (const float*)d_in[11];
  const float* lnb = (const float*)d_in[12];

  float* ws = (float*)d_ws;
  float* Wc = ws;                              // 32768 f32
  float* x1 = ws + 32768;                      // 4194304 f32
  unsigned short* y = (unsigned short*)(ws + 32768 + 4194304); // 8388608 bf16

  precomp_wc<<<32, 256, 0, stream>>>(fW, oW, Wc);
  mamba_dir<<<1024, 256, 0, stream>>>(x, x1, y, Wp, cw, cb, dtb, Al, Dp,
                                      nw, lnw, lnb, Wc, 0);
  combine0<<<512, 256, 0, stream>>>(x, y, fb, x1);
  mamba_dir<<<1024, 256, 0, stream>>>(x, x1, y, Wp, cw, cb, dtb, Al, Dp,
                                      nw, lnw, lnb, Wc, 1);
  combine1<<<512, 256, 0, stream>>>(x1, y, fb + 64, (float*)d_out);
}

// Round 5
// 5479.723 us; speedup vs baseline: 1.3484x; 1.1929x over previous
//
#include <hip/hip_runtime.h>

#define EPSV 1e-5f

__device__ __forceinline__ float sigmoidf_(float x) {
  return 1.f / (1.f + __expf(-x));
}
__device__ __forceinline__ unsigned short f2bf(float f) {
  unsigned int u = __float_as_uint(f);
  u += 0x7fffu + ((u >> 16) & 1u);
  return (unsigned short)(u >> 16);
}
__device__ __forceinline__ float bfu(unsigned short h) {
  union { unsigned int u; float f; } t; t.u = ((unsigned int)h) << 16; return t.f;
}

// ---------------------------------------------------------------------------
// W_comb[i][m][k] = sum_j fusion_W[p][m][d*64+j] * out_W[i][j][k]
// ---------------------------------------------------------------------------
__global__ __launch_bounds__(256) void precomp_wc(
    const float* __restrict__ fW,   // (2,64,128)
    const float* __restrict__ oW,   // (4,64,128)
    float* __restrict__ Wc)         // (4,64,128)
{
  const int bi = blockIdx.x;
  const int i = bi >> 3, mg = bi & 7;
  const int m = (mg << 3) + (threadIdx.x >> 5);
  const int k0 = (threadIdx.x & 31) << 2;
  const int p = i >> 1, d = i & 1;
  const float* fr = fW + p * 8192 + m * 128 + d * 64;
  const float* orow = oW + i * 8192 + k0;
  float a0 = 0.f, a1 = 0.f, a2 = 0.f, a3 = 0.f;
  for (int j = 0; j < 64; ++j) {
    const float f = fr[j];
    const float4 o4 = *(const float4*)(orow + j * 128);
    a0 += f * o4.x; a1 += f * o4.y; a2 += f * o4.z; a3 += f * o4.w;
  }
  float* out = Wc + i * 8192 + m * 128 + k0;
  out[0] = a0; out[1] = a1; out[2] = a2; out[3] = a3;
}

// ---------------------------------------------------------------------------
// Transpose in_proj_W: WpT[ip][k][o] (row stride 388) = Wp[ip][o][k].
// Lets mamba_dir stream weights coalesced with ZERO per-thread caching.
// ---------------------------------------------------------------------------
__global__ __launch_bounds__(256) void precomp_wpt(
    const float* __restrict__ Wp, float* __restrict__ WpT)
{
  const int ip = blockIdx.x;
  const float* src = Wp + (size_t)ip * 24704;
  float* dst = WpT + (size_t)ip * (64 * 388);
  for (int idx = threadIdx.x; idx < 24704; idx += 256) {
    const int o = idx >> 6, k = idx & 63;
    dst[k * 388 + o] = src[idx];
  }
}

// ---------------------------------------------------------------------------
// One block = one (sequence, direction). 1024 blocks/phase. CH=8 tokens.
// LDS 20.6 KB. in_proj streams transposed weights (coalesced, L2-resident);
// per-thread live set ~70 VGPRs -> no scratch spill (rounds 2-4 all spilled
// via the w[64] register cache).
// ---------------------------------------------------------------------------
__global__ __launch_bounds__(256, 2) void mamba_dir(
    const float* __restrict__ xin,   // canonical x (4,64,128,128) f32
    const float* __restrict__ x1,    // phase1 input [b][f][t][c] f32
    unsigned short* __restrict__ ybuf, // bf16 [dir][seq][pos][64]
    const float* __restrict__ WpT,   // transposed in_proj (4,64,388)
    const float* __restrict__ cwA, const float* __restrict__ cbA,
    const float* __restrict__ dtbA, const float* __restrict__ AlA,
    const float* __restrict__ DpA, const float* __restrict__ nwA,
    const float* __restrict__ lnwA, const float* __restrict__ lnbA,
    const float* __restrict__ WcA,
    int phase)
{
  __shared__ float sZ[8 * 388];   // z(0-127)|xBC(128-383)|dtraw(384-385); y/g overlay 128-255
  __shared__ float sX[8][256];    // conv+silu out; u aliased in cols 0-63 pre-conv

  const int tid = threadIdx.x;
  const int blk = blockIdx.x;
  const int seq = blk >> 1, dir = blk & 1;
  const int b = seq >> 7, q = seq & 127;
  const int ip = (phase << 1) + dir;
  const float* Wt = WpT + (size_t)ip * (64 * 388);
  const float* Wc = WcA + (size_t)ip * 8192;
  const float dtb0 = dtbA[ip * 2], dtb1 = dtbA[ip * 2 + 1];
  const float nA0 = -__expf(AlA[ip * 2]), nA1 = -__expf(AlA[ip * 2 + 1]);
  const float Dp0 = DpA[ip * 2], Dp1 = DpA[ip * 2 + 1];
  const float4 cw4 = *(const float4*)(cwA + ip * 1024 + (tid << 2));
  const float cbias = cbA[ip * 256 + tid];
  float ch0 = 0.f, ch1 = 0.f, ch2 = 0.f;   // conv history (registers)
  float S[32];                              // scan state (registers)
  #pragma unroll
  for (int i = 0; i < 32; ++i) S[i] = 0.f;

  const size_t sb = phase ? ((size_t)b * 1048576 + (size_t)q * 8192)
                          : ((size_t)b * 1048576 + (size_t)q * 128);
  const float* src = phase ? x1 : xin;

  for (int ck = 0; ck < 16; ++ck) {
    // ---- 1. load 8 pos x 64 ch into sX (u region) ----
    if (phase) {
      const int pos = tid >> 5, cl = (tid & 31) << 1;
      const int st = (ck << 3) + pos, rp = dir ? (127 - st) : st;
      const float2 v = *(const float2*)(src + sb + (size_t)rp * 64 + cl);
      sX[pos][cl] = v.x; sX[pos][cl + 1] = v.y;
    } else {
      const int pos = tid & 7, c0 = (tid >> 3) << 1;
      const int st = (ck << 3) + pos, rp = dir ? (127 - st) : st;
      const float* p = src + sb + rp;
      sX[pos][c0]     = p[(size_t)c0 * 16384];
      sX[pos][c0 + 1] = p[(size_t)(c0 + 1) * 16384];
    }
    __syncthreads();
    // ---- 2. layernorm (in place) ----
    {
      const int pos = tid >> 5, cl = (tid & 31) << 1;
      const float v0 = sX[pos][cl], v1 = sX[pos][cl + 1];
      float sm = v0 + v1, s2 = v0 * v0 + v1 * v1;
      sm += __shfl_xor(sm, 1);  s2 += __shfl_xor(s2, 1);
      sm += __shfl_xor(sm, 2);  s2 += __shfl_xor(s2, 2);
      sm += __shfl_xor(sm, 4);  s2 += __shfl_xor(s2, 4);
      sm += __shfl_xor(sm, 8);  s2 += __shfl_xor(s2, 8);
      sm += __shfl_xor(sm, 16); s2 += __shfl_xor(s2, 16);
      const float mean = sm * (1.f / 64.f);
      const float inv = rsqrtf(s2 * (1.f / 64.f) - mean * mean + EPSV);
      const int lb = (phase << 6) + cl;
      sX[pos][cl]     = (v0 - mean) * inv * lnwA[lb] + lnbA[lb];
      sX[pos][cl + 1] = (v1 - mean) * inv * lnwA[lb + 1] + lnbA[lb + 1];
    }
    __syncthreads();
    // ---- 3. in_proj: stream coalesced transposed weights, acc[8] in regs ----
    #pragma unroll
    for (int r = 0; r < 2; ++r) {
      const int o = tid + (r << 8);
      if (o < 386) {
        const float* wt = Wt + o;
        float acc[8];
        #pragma unroll
        for (int lt = 0; lt < 8; ++lt) acc[lt] = 0.f;
        #pragma unroll
        for (int k4 = 0; k4 < 16; ++k4) {
          const float w0 = wt[(k4 * 4 + 0) * 388];
          const float w1 = wt[(k4 * 4 + 1) * 388];
          const float w2 = wt[(k4 * 4 + 2) * 388];
          const float w3 = wt[(k4 * 4 + 3) * 388];
          #pragma unroll
          for (int lt = 0; lt < 8; ++lt) {
            const float4 u4 = *(const float4*)(&sX[lt][k4 << 2]);
            acc[lt] += w0 * u4.x + w1 * u4.y + w2 * u4.z + w3 * u4.w;
          }
        }
        #pragma unroll
        for (int lt = 0; lt < 8; ++lt) sZ[lt * 388 + o] = acc[lt];
      }
    }
    __syncthreads();
    // ---- 4. conv(4,causal)+silu; history in registers ----
    {
      float a0 = ch0, a1 = ch1, a2 = ch2;
      #pragma unroll
      for (int lt = 0; lt < 8; ++lt) {
        const float a3 = sZ[lt * 388 + 128 + tid];
        const float acc = cbias + a0 * cw4.x + a1 * cw4.y + a2 * cw4.z + a3 * cw4.w;
        sX[lt][tid] = acc * sigmoidf_(acc);
        a0 = a1; a1 = a2; a2 = a3;
      }
      ch0 = a0; ch1 = a1; ch2 = a2;
    }
    __syncthreads();
    // ---- 5. selective scan: 128 rows x 2 halves; dt/dA recomputed in place ----
    {
      const int row = tid >> 1, half = tid & 1, hh = row >> 6;
      const int boff = 128 + (half << 5);
      const float dtbh = hh ? dtb1 : dtb0, nAh = hh ? nA1 : nA0;
      #pragma unroll
      for (int lt = 0; lt < 8; ++lt) {
        const float rawv = sZ[lt * 388 + 384 + hh] + dtbh;
        const float dtv = (rawv > 20.f) ? rawv : log1pf(__expf(rawv));
        const float dA = __expf(dtv * nAh);
        const float dtx = dtv * sX[lt][row];
        const float4* Bp = (const float4*)(&sX[lt][boff]);
        const float4* Cp = (const float4*)(&sX[lt][boff + 64]);
        float yp = 0.f;
        #pragma unroll
        for (int i = 0; i < 8; ++i) {
          const float4 Bv = Bp[i], Cv = Cp[i];
          S[i * 4 + 0] = S[i * 4 + 0] * dA + dtx * Bv.x; yp += S[i * 4 + 0] * Cv.x;
          S[i * 4 + 1] = S[i * 4 + 1] * dA + dtx * Bv.y; yp += S[i * 4 + 1] * Cv.y;
          S[i * 4 + 2] = S[i * 4 + 2] * dA + dtx * Bv.z; yp += S[i * 4 + 2] * Cv.z;
          S[i * 4 + 3] = S[i * 4 + 3] * dA + dtx * Bv.w; yp += S[i * 4 + 3] * Cv.w;
        }
        yp += __shfl_xor(yp, 1);
        if (!half) sZ[lt * 388 + 128 + row] = yp;   // y overlays dead xBC region
      }
    }
    __syncthreads();
    // ---- 6. gate with silu(z) + rmsnorm ----
    {
      const int lt = tid >> 5, c0 = (tid & 31) << 2;
      const float4 yv = *(const float4*)(&sZ[lt * 388 + 128 + c0]);
      const float4 zv = *(const float4*)(&sZ[lt * 388 + c0]);
      const float4 xv = *(const float4*)(&sX[lt][c0]);
      const float dp = (c0 & 64) ? Dp1 : Dp0;
      const float g0 = (yv.x + dp * xv.x) * (zv.x * sigmoidf_(zv.x));
      const float g1 = (yv.y + dp * xv.y) * (zv.y * sigmoidf_(zv.y));
      const float g2 = (yv.z + dp * xv.z) * (zv.z * sigmoidf_(zv.z));
      const float g3 = (yv.w + dp * xv.w) * (zv.w * sigmoidf_(zv.w));
      float ssq = g0 * g0 + g1 * g1 + g2 * g2 + g3 * g3;
      ssq += __shfl_xor(ssq, 1);
      ssq += __shfl_xor(ssq, 2);
      ssq += __shfl_xor(ssq, 4);
      ssq += __shfl_xor(ssq, 8);
      ssq += __shfl_xor(ssq, 16);
      const float sc = rsqrtf(ssq * (1.f / 128.f) + EPSV);
      const float4 nw4 = *(const float4*)(nwA + ip * 128 + c0);
      float4 gv;
      gv.x = g0 * sc * nw4.x; gv.y = g1 * sc * nw4.y;
      gv.z = g2 * sc * nw4.z; gv.w = g3 * sc * nw4.w;
      *(float4*)(&sZ[lt * 388 + 128 + c0]) = gv;
    }
    __syncthreads();
    // ---- 7. fused out_proj+fusion matmul -> compact bf16 store ----
    {
      const int lt = tid >> 5, mb = tid & 31;
      const float4* gy = (const float4*)(&sZ[lt * 388 + 128]);
      const float4* wa = (const float4*)(Wc + ((size_t)mb << 7));
      const float4* wb = (const float4*)(Wc + ((size_t)(mb + 32) << 7));
      float acc0 = 0.f, acc1 = 0.f;
      #pragma unroll
      for (int i = 0; i < 32; ++i) {
        const float4 gv = gy[i], av = wa[i], bv = wb[i];
        acc0 += av.x * gv.x + av.y * gv.y + av.z * gv.z + av.w * gv.w;
        acc1 += bv.x * gv.x + bv.y * gv.y + bv.z * gv.z + bv.w * gv.w;
      }
      const int st = (ck << 3) + lt, rp = dir ? (127 - st) : st;
      unsigned short* yo = ybuf + (((size_t)(dir * 512 + seq) * 128 + rp) << 6);
      yo[mb] = f2bf(acc0);
      yo[mb + 32] = f2bf(acc1);
    }
    __syncthreads();
  }
}

// ---------------------------------------------------------------------------
// combine0: x1[b][f][t][c] = x[b][c][t][f] + yf + yb + fb0[c]   (all coalesced)
// ---------------------------------------------------------------------------
__global__ __launch_bounds__(256) void combine0(
    const float* __restrict__ x, const unsigned short* __restrict__ ybuf,
    const float* __restrict__ fb, float* __restrict__ x1)
{
  __shared__ float T[64 * 132];
  const int tid = threadIdx.x, blk = blockIdx.x;
  const int b = blk >> 7, t = blk & 127;
  {
    const int c = tid >> 2, f0 = (tid & 3) << 5;
    const float* xp = x + (((size_t)(b * 64 + c) * 128 + t) << 7) + f0;
    float* tp = &T[c * 132 + f0];
    #pragma unroll
    for (int j = 0; j < 8; ++j)
      *(float4*)(tp + (j << 2)) = *(const float4*)(xp + (j << 2));
  }
  __syncthreads();
  {
    const int f = tid >> 1, cb = (tid & 1) << 5;
    const size_t s0 = (size_t)b * 128 + t;
    const unsigned short* yf = ybuf + ((s0 * 128 + f) << 6) + cb;
    const unsigned short* yb = ybuf + (((s0 + 512) * 128 + f) << 6) + cb;
    float* op = x1 + (((size_t)(b * 128 + f) * 128 + t) << 6) + cb;
    #pragma unroll
    for (int j = 0; j < 32; j += 4) {
      float4 v;
      v.x = T[(cb + j + 0) * 132 + f] + bfu(yf[j + 0]) + bfu(yb[j + 0]) + fb[cb + j + 0];
      v.y = T[(cb + j + 1) * 132 + f] + bfu(yf[j + 1]) + bfu(yb[j + 1]) + fb[cb + j + 1];
      v.z = T[(cb + j + 2) * 132 + f] + bfu(yf[j + 2]) + bfu(yb[j + 2]) + fb[cb + j + 2];
      v.w = T[(cb + j + 3) * 132 + f] + bfu(yf[j + 3]) + bfu(yb[j + 3]) + fb[cb + j + 3];
      *(float4*)(op + j) = v;
    }
  }
}

// ---------------------------------------------------------------------------
// combine1: out[b][c][t][f] = x1[b][f][t][c] + yf + yb + fb1[c]  (all coalesced)
// ---------------------------------------------------------------------------
__global__ __launch_bounds__(256) void combine1(
    const float* __restrict__ x1, const unsigned short* __restrict__ ybuf,
    const float* __restrict__ fb, float* __restrict__ out)
{
  __shared__ float T[128 * 68];
  const int tid = threadIdx.x, blk = blockIdx.x;
  const int b = blk >> 7, t = blk & 127;
  {
    const int f = tid >> 1, cb = (tid & 1) << 5;
    const size_t s1 = (size_t)b * 128 + f;
    const float* xp = x1 + ((s1 * 128 + t) << 6) + cb;
    const unsigned short* yf = ybuf + ((s1 * 128 + t) << 6) + cb;
    const unsigned short* yb = ybuf + (((s1 + 512) * 128 + t) << 6) + cb;
    float* tp = &T[f * 68 + cb];
    #pragma unroll
    for (int j = 0; j < 32; ++j)
      tp[j] = xp[j] + bfu(yf[j]) + bfu(yb[j]) + fb[cb + j];
  }
  __syncthreads();
  {
    const int c = tid >> 2, f0 = (tid & 3) << 5;
    float* op = out + (((size_t)(b * 64 + c) * 128 + t) << 7) + f0;
    #pragma unroll
    for (int j = 0; j < 32; j += 4) {
      float4 v;
      v.x = T[(f0 + j + 0) * 68 + c];
      v.y = T[(f0 + j + 1) * 68 + c];
      v.z = T[(f0 + j + 2) * 68 + c];
      v.w = T[(f0 + j + 3) * 68 + c];
      *(float4*)(op + j) = v;
    }
  }
}

extern "C" void kernel_launch(void* const* d_in, const int* in_sizes, int n_in,
                              void* d_out, int out_size, void* d_ws, size_t ws_size,
                              hipStream_t stream) {
  const float* x   = (const float*)d_in[0];
  const float* Wp  = (const float*)d_in[1];
  const float* cw  = (const float*)d_in[2];
  const float* cb  = (const float*)d_in[3];
  const float* dtb = (const float*)d_in[4];
  const float* Al  = (const float*)d_in[5];
  const float* Dp  = (const float*)d_in[6];
  const float* nw  = (const float*)d_in[7];
  const float* oW  = (const float*)d_in[8];
  const float* fW  = (const float*)d_in[9];
  const float* fb  = (const float*)d_in[10];
  const float* lnw = (const float*)d_in[11];
  const float* lnb = (const float*)d_in[12];

  float* ws = (float*)d_ws;
  float* Wc  = ws;                             // 32768 f32
  float* WpT = ws + 32768;                     // 4*64*388 = 99328 f32
  float* x1  = WpT + 99328;                    // 4194304 f32
  unsigned short* y = (unsigned short*)(x1 + 4194304); // 8388608 bf16

  precomp_wc<<<32, 256, 0, stream>>>(fW, oW, Wc);
  precomp_wpt<<<4, 256, 0, stream>>>(Wp, WpT);
  mamba_dir<<<1024, 256, 0, stream>>>(x, x1, y, WpT, cw, cb, dtb, Al, Dp,
                                      nw, lnw, lnb, Wc, 0);
  combine0<<<512, 256, 0, stream>>>(x, y, fb, x1);
  mamba_dir<<<1024, 256, 0, stream>>>(x, x1, y, WpT, cw, cb, dtb, Al, Dp,
                                      nw, lnw, lnb, Wc, 1);
  combine1<<<512, 256, 0, stream>>>(x1, y, fb + 64, (float*)d_out);
}

// Round 6
// 1284.642 us; speedup vs baseline: 5.7518x; 4.2656x over previous
//
#include <hip/hip_runtime.h>

#define EPSV 1e-5f

__device__ __forceinline__ float sigmoidf_(float x) {
  return 1.f / (1.f + __expf(-x));
}
__device__ __forceinline__ unsigned short f2bf(float f) {
  unsigned int u = __float_as_uint(f);
  u += 0x7fffu + ((u >> 16) & 1u);
  return (unsigned short)(u >> 16);
}
__device__ __forceinline__ float bfu(unsigned short h) {
  union { unsigned int u; float f; } t; t.u = ((unsigned int)h) << 16; return t.f;
}
__device__ __forceinline__ float bflo(unsigned int u) {
  union { unsigned int x; float f; } t; t.x = u << 16; return t.f;
}
__device__ __forceinline__ float bfhi(unsigned int u) {
  union { unsigned int x; float f; } t; t.x = u & 0xffff0000u; return t.f;
}

// ---------------------------------------------------------------------------
// W_comb[i][m][k] = sum_j fusion_W[p][m][d*64+j] * out_W[i][j][k]
// ---------------------------------------------------------------------------
__global__ __launch_bounds__(256) void precomp_wc(
    const float* __restrict__ fW,   // (2,64,128)
    const float* __restrict__ oW,   // (4,64,128)
    float* __restrict__ Wc)         // (4,64,128)
{
  const int bi = blockIdx.x;
  const int i = bi >> 3, mg = bi & 7;
  const int m = (mg << 3) + (threadIdx.x >> 5);
  const int k0 = (threadIdx.x & 31) << 2;
  const int p = i >> 1, d = i & 1;
  const float* fr = fW + p * 8192 + m * 128 + d * 64;
  const float* orow = oW + i * 8192 + k0;
  float a0 = 0.f, a1 = 0.f, a2 = 0.f, a3 = 0.f;
  for (int j = 0; j < 64; ++j) {
    const float f = fr[j];
    const float4 o4 = *(const float4*)(orow + j * 128);
    a0 += f * o4.x; a1 += f * o4.y; a2 += f * o4.z; a3 += f * o4.w;
  }
  float* out = Wc + i * 8192 + m * 128 + k0;
  out[0] = a0; out[1] = a1; out[2] = a2; out[3] = a3;
}

// ---------------------------------------------------------------------------
// in_proj weights -> bf16, padded rows [o][72] (144 B: 16B-aligned for
// ds_read_b128, 36-dword bank rotation). Staged once per block into LDS.
// ---------------------------------------------------------------------------
__global__ __launch_bounds__(256) void precomp_wpb(
    const float* __restrict__ Wp, unsigned short* __restrict__ WpB)
{
  const int ip = blockIdx.x;
  const float* src = Wp + (size_t)ip * 24704;
  unsigned short* dst = WpB + (size_t)ip * (386 * 72);
  for (int idx = threadIdx.x; idx < 386 * 72; idx += 256) {
    const int o = idx / 72, k = idx - o * 72;
    dst[idx] = (k < 64) ? f2bf(src[o * 64 + k]) : (unsigned short)0;
  }
}

// ---------------------------------------------------------------------------
// One block = one (sequence, direction). 1024 blocks/phase. CH=8 tokens.
// Weights: in_proj bf16 in LDS (loaded ONCE), Wc in 32 regs/thread.
// LDS 74.4 KB -> 2 blocks/CU; LDS-limited occupancy means VGPRs are free
// up to 256 -> no spill (r3-r5 disease).
// ---------------------------------------------------------------------------
__global__ __launch_bounds__(256, 2) void mamba_dir(
    const float* __restrict__ xin,   // canonical x (4,64,128,128) f32
    const float* __restrict__ x1,    // phase1 input [b][f][t][c] f32
    unsigned short* __restrict__ ybuf, // bf16 [dir][seq][pos][64]
    const unsigned short* __restrict__ WpB, // bf16 padded (4,386,72)
    const float* __restrict__ cwA, const float* __restrict__ cbA,
    const float* __restrict__ dtbA, const float* __restrict__ AlA,
    const float* __restrict__ DpA, const float* __restrict__ nwA,
    const float* __restrict__ lnwA, const float* __restrict__ lnbA,
    const float* __restrict__ WcA,
    int phase)
{
  __shared__ __align__(16) unsigned short sW[386 * 72]; // 55.6 KB bf16 weights
  __shared__ float sZ[8 * 388];   // z|xBC|dtraw; y/g overlay 128-255
  __shared__ float sX[8][256];    // conv+silu out; u aliased cols 0-63 pre-conv

  const int tid = threadIdx.x;
  const int blk = blockIdx.x;
  const int seq = blk >> 1, dir = blk & 1;
  const int b = seq >> 7, q = seq & 127;
  const int ip = (phase << 1) + dir;
  const float dtb0 = dtbA[ip * 2], dtb1 = dtbA[ip * 2 + 1];
  const float nA0 = -__expf(AlA[ip * 2]), nA1 = -__expf(AlA[ip * 2 + 1]);
  const float Dp0 = DpA[ip * 2], Dp1 = DpA[ip * 2 + 1];
  const float4 cw4 = *(const float4*)(cwA + ip * 1024 + (tid << 2));
  const float cbias = cbA[ip * 256 + tid];
  float ch0 = 0.f, ch1 = 0.f, ch2 = 0.f;   // conv history (registers)
  float S[32];                              // scan state (registers)
  #pragma unroll
  for (int i = 0; i < 32; ++i) S[i] = 0.f;

  // stage in_proj weights into LDS once (coalesced dword copy)
  {
    const unsigned int* srcw =
        (const unsigned int*)(WpB + (size_t)ip * (386 * 72));
    unsigned int* dw = (unsigned int*)sW;
    for (int i = tid; i < 386 * 36; i += 256) dw[i] = srcw[i];
  }
  // Wc into registers: thread owns (m_own = tid>>2, kq = tid&3) -> 32 floats
  const int m_own = tid >> 2, kq = tid & 3;
  float wcr[32];
  {
    const float4* wsrc =
        (const float4*)(WcA + (size_t)ip * 8192 + (m_own << 7) + (kq << 5));
    #pragma unroll
    for (int i = 0; i < 8; ++i) {
      const float4 v = wsrc[i];
      wcr[i * 4 + 0] = v.x; wcr[i * 4 + 1] = v.y;
      wcr[i * 4 + 2] = v.z; wcr[i * 4 + 3] = v.w;
    }
  }
  __syncthreads();

  const size_t sb = phase ? ((size_t)b * 1048576 + (size_t)q * 8192)
                          : ((size_t)b * 1048576 + (size_t)q * 128);
  const float* src = phase ? x1 : xin;

  for (int ck = 0; ck < 16; ++ck) {
    // ---- 1. load 8 pos x 64 ch into sX (u region) ----
    if (phase) {
      const int pos = tid >> 5, cl = (tid & 31) << 1;
      const int st = (ck << 3) + pos, rp = dir ? (127 - st) : st;
      const float2 v = *(const float2*)(src + sb + (size_t)rp * 64 + cl);
      sX[pos][cl] = v.x; sX[pos][cl + 1] = v.y;
    } else {
      const int pos = tid & 7, c0 = (tid >> 3) << 1;
      const int st = (ck << 3) + pos, rp = dir ? (127 - st) : st;
      const float* p = src + sb + rp;
      sX[pos][c0]     = p[(size_t)c0 * 16384];
      sX[pos][c0 + 1] = p[(size_t)(c0 + 1) * 16384];
    }
    __syncthreads();
    // ---- 2. layernorm (in place) ----
    {
      const int pos = tid >> 5, cl = (tid & 31) << 1;
      const float v0 = sX[pos][cl], v1 = sX[pos][cl + 1];
      float sm = v0 + v1, s2 = v0 * v0 + v1 * v1;
      sm += __shfl_xor(sm, 1);  s2 += __shfl_xor(s2, 1);
      sm += __shfl_xor(sm, 2);  s2 += __shfl_xor(s2, 2);
      sm += __shfl_xor(sm, 4);  s2 += __shfl_xor(s2, 4);
      sm += __shfl_xor(sm, 8);  s2 += __shfl_xor(s2, 8);
      sm += __shfl_xor(sm, 16); s2 += __shfl_xor(s2, 16);
      const float mean = sm * (1.f / 64.f);
      const float inv = rsqrtf(s2 * (1.f / 64.f) - mean * mean + EPSV);
      const int lb = (phase << 6) + cl;
      sX[pos][cl]     = (v0 - mean) * inv * lnwA[lb] + lnbA[lb];
      sX[pos][cl + 1] = (v1 - mean) * inv * lnwA[lb + 1] + lnbA[lb + 1];
    }
    __syncthreads();
    // ---- 3. in_proj from LDS bf16 weights (ds_read_b128 rows) ----
    #pragma unroll
    for (int r = 0; r < 2; ++r) {
      const int o = tid + (r << 8);
      if (o < 386) {
        const uint4* wrow = (const uint4*)(&sW[o * 72]);
        float acc[8];
        #pragma unroll
        for (int lt = 0; lt < 8; ++lt) acc[lt] = 0.f;
        #pragma unroll
        for (int k8 = 0; k8 < 8; ++k8) {
          const uint4 wv = wrow[k8];
          const float w0 = bflo(wv.x), w1 = bfhi(wv.x);
          const float w2 = bflo(wv.y), w3 = bfhi(wv.y);
          const float w4 = bflo(wv.z), w5 = bfhi(wv.z);
          const float w6 = bflo(wv.w), w7 = bfhi(wv.w);
          #pragma unroll
          for (int lt = 0; lt < 8; ++lt) {
            const float4 ua = *(const float4*)(&sX[lt][k8 << 3]);
            const float4 ub = *(const float4*)(&sX[lt][(k8 << 3) + 4]);
            acc[lt] += w0 * ua.x + w1 * ua.y + w2 * ua.z + w3 * ua.w +
                       w4 * ub.x + w5 * ub.y + w6 * ub.z + w7 * ub.w;
          }
        }
        #pragma unroll
        for (int lt = 0; lt < 8; ++lt) sZ[lt * 388 + o] = acc[lt];
      }
    }
    __syncthreads();
    // ---- 4. conv(4,causal)+silu; history in registers ----
    {
      float a0 = ch0, a1 = ch1, a2 = ch2;
      #pragma unroll
      for (int lt = 0; lt < 8; ++lt) {
        const float a3 = sZ[lt * 388 + 128 + tid];
        const float acc = cbias + a0 * cw4.x + a1 * cw4.y + a2 * cw4.z + a3 * cw4.w;
        sX[lt][tid] = acc * sigmoidf_(acc);
        a0 = a1; a1 = a2; a2 = a3;
      }
      ch0 = a0; ch1 = a1; ch2 = a2;
    }
    __syncthreads();
    // ---- 5. selective scan: 128 rows x 2 halves; dt/dA recomputed ----
    {
      const int row = tid >> 1, half = tid & 1, hh = row >> 6;
      const int boff = 128 + (half << 5);
      const float dtbh = hh ? dtb1 : dtb0, nAh = hh ? nA1 : nA0;
      #pragma unroll
      for (int lt = 0; lt < 8; ++lt) {
        const float rawv = sZ[lt * 388 + 384 + hh] + dtbh;
        const float dtv = (rawv > 20.f) ? rawv : log1pf(__expf(rawv));
        const float dA = __expf(dtv * nAh);
        const float dtx = dtv * sX[lt][row];
        const float4* Bp = (const float4*)(&sX[lt][boff]);
        const float4* Cp = (const float4*)(&sX[lt][boff + 64]);
        float yp = 0.f;
        #pragma unroll
        for (int i = 0; i < 8; ++i) {
          const float4 Bv = Bp[i], Cv = Cp[i];
          S[i * 4 + 0] = S[i * 4 + 0] * dA + dtx * Bv.x; yp += S[i * 4 + 0] * Cv.x;
          S[i * 4 + 1] = S[i * 4 + 1] * dA + dtx * Bv.y; yp += S[i * 4 + 1] * Cv.y;
          S[i * 4 + 2] = S[i * 4 + 2] * dA + dtx * Bv.z; yp += S[i * 4 + 2] * Cv.z;
          S[i * 4 + 3] = S[i * 4 + 3] * dA + dtx * Bv.w; yp += S[i * 4 + 3] * Cv.w;
        }
        yp += __shfl_xor(yp, 1);
        if (!half) sZ[lt * 388 + 128 + row] = yp;   // y overlays dead xBC
      }
    }
    __syncthreads();
    // ---- 6. gate with silu(z) + rmsnorm ----
    {
      const int lt = tid >> 5, c0 = (tid & 31) << 2;
      const float4 yv = *(const float4*)(&sZ[lt * 388 + 128 + c0]);
      const float4 zv = *(const float4*)(&sZ[lt * 388 + c0]);
      const float4 xv = *(const float4*)(&sX[lt][c0]);
      const float dp = (c0 & 64) ? Dp1 : Dp0;
      const float g0 = (yv.x + dp * xv.x) * (zv.x * sigmoidf_(zv.x));
      const float g1 = (yv.y + dp * xv.y) * (zv.y * sigmoidf_(zv.y));
      const float g2 = (yv.z + dp * xv.z) * (zv.z * sigmoidf_(zv.z));
      const float g3 = (yv.w + dp * xv.w) * (zv.w * sigmoidf_(zv.w));
      float ssq = g0 * g0 + g1 * g1 + g2 * g2 + g3 * g3;
      ssq += __shfl_xor(ssq, 1);
      ssq += __shfl_xor(ssq, 2);
      ssq += __shfl_xor(ssq, 4);
      ssq += __shfl_xor(ssq, 8);
      ssq += __shfl_xor(ssq, 16);
      const float sc = rsqrtf(ssq * (1.f / 128.f) + EPSV);
      const float4 nw4 = *(const float4*)(nwA + ip * 128 + c0);
      float4 gv;
      gv.x = g0 * sc * nw4.x; gv.y = g1 * sc * nw4.y;
      gv.z = g2 * sc * nw4.z; gv.w = g3 * sc * nw4.w;
      *(float4*)(&sZ[lt * 388 + 128 + c0]) = gv;
    }
    __syncthreads();
    // ---- 7. out-matmul from register weights + shfl reduce over kq ----
    {
      const int koff = 128 + (kq << 5);
      #pragma unroll
      for (int lt = 0; lt < 8; ++lt) {
        const float4* gp = (const float4*)(&sZ[lt * 388 + koff]);
        float pth = 0.f;
        #pragma unroll
        for (int i = 0; i < 8; ++i) {
          const float4 g4 = gp[i];
          pth += wcr[i * 4 + 0] * g4.x + wcr[i * 4 + 1] * g4.y +
                 wcr[i * 4 + 2] * g4.z + wcr[i * 4 + 3] * g4.w;
        }
        pth += __shfl_xor(pth, 1);
        pth += __shfl_xor(pth, 2);
        if (kq == 0) {
          const int st = (ck << 3) + lt, rp = dir ? (127 - st) : st;
          ybuf[(((size_t)(dir * 512 + seq) * 128 + rp) << 6) + m_own] = f2bf(pth);
        }
      }
    }
    __syncthreads();
  }
}

// ---------------------------------------------------------------------------
// combine0: x1[b][f][t][c] = x[b][c][t][f] + yf + yb + fb0[c]   (coalesced)
// ---------------------------------------------------------------------------
__global__ __launch_bounds__(256) void combine0(
    const float* __restrict__ x, const unsigned short* __restrict__ ybuf,
    const float* __restrict__ fb, float* __restrict__ x1)
{
  __shared__ float T[64 * 132];
  const int tid = threadIdx.x, blk = blockIdx.x;
  const int b = blk >> 7, t = blk & 127;
  {
    const int c = tid >> 2, f0 = (tid & 3) << 5;
    const float* xp = x + (((size_t)(b * 64 + c) * 128 + t) << 7) + f0;
    float* tp = &T[c * 132 + f0];
    #pragma unroll
    for (int j = 0; j < 8; ++j)
      *(float4*)(tp + (j << 2)) = *(const float4*)(xp + (j << 2));
  }
  __syncthreads();
  {
    const int f = tid >> 1, cb = (tid & 1) << 5;
    const size_t s0 = (size_t)b * 128 + t;
    const unsigned short* yf = ybuf + ((s0 * 128 + f) << 6) + cb;
    const unsigned short* yb = ybuf + (((s0 + 512) * 128 + f) << 6) + cb;
    float* op = x1 + (((size_t)(b * 128 + f) * 128 + t) << 6) + cb;
    #pragma unroll
    for (int j = 0; j < 32; j += 4) {
      float4 v;
      v.x = T[(cb + j + 0) * 132 + f] + bfu(yf[j + 0]) + bfu(yb[j + 0]) + fb[cb + j + 0];
      v.y = T[(cb + j + 1) * 132 + f] + bfu(yf[j + 1]) + bfu(yb[j + 1]) + fb[cb + j + 1];
      v.z = T[(cb + j + 2) * 132 + f] + bfu(yf[j + 2]) + bfu(yb[j + 2]) + fb[cb + j + 2];
      v.w = T[(cb + j + 3) * 132 + f] + bfu(yf[j + 3]) + bfu(yb[j + 3]) + fb[cb + j + 3];
      *(float4*)(op + j) = v;
    }
  }
}

// ---------------------------------------------------------------------------
// combine1: out[b][c][t][f] = x1[b][f][t][c] + yf + yb + fb1[c]  (coalesced)
// ---------------------------------------------------------------------------
__global__ __launch_bounds__(256) void combine1(
    const float* __restrict__ x1, const unsigned short* __restrict__ ybuf,
    const float* __restrict__ fb, float* __restrict__ out)
{
  __shared__ float T[128 * 68];
  const int tid = threadIdx.x, blk = blockIdx.x;
  const int b = blk >> 7, t = blk & 127;
  {
    const int f = tid >> 1, cb = (tid & 1) << 5;
    const size_t s1 = (size_t)b * 128 + f;
    const float* xp = x1 + ((s1 * 128 + t) << 6) + cb;
    const unsigned short* yf = ybuf + ((s1 * 128 + t) << 6) + cb;
    const unsigned short* yb = ybuf + (((s1 + 512) * 128 + t) << 6) + cb;
    float* tp = &T[f * 68 + cb];
    #pragma unroll
    for (int j = 0; j < 32; ++j)
      tp[j] = xp[j] + bfu(yf[j]) + bfu(yb[j]) + fb[cb + j];
  }
  __syncthreads();
  {
    const int c = tid >> 2, f0 = (tid & 3) << 5;
    float* op = out + (((size_t)(b * 64 + c) * 128 + t) << 7) + f0;
    #pragma unroll
    for (int j = 0; j < 32; j += 4) {
      float4 v;
      v.x = T[(f0 + j + 0) * 68 + c];
      v.y = T[(f0 + j + 1) * 68 + c];
      v.z = T[(f0 + j + 2) * 68 + c];
      v.w = T[(f0 + j + 3) * 68 + c];
      *(float4*)(op + j) = v;
    }
  }
}

extern "C" void kernel_launch(void* const* d_in, const int* in_sizes, int n_in,
                              void* d_out, int out_size, void* d_ws, size_t ws_size,
                              hipStream_t stream) {
  const float* x   = (const float*)d_in[0];
  const float* Wp  = (const float*)d_in[1];
  const float* cw  = (const float*)d_in[2];
  const float* cb  = (const float*)d_in[3];
  const float* dtb = (const float*)d_in[4];
  const float* Al  = (const float*)d_in[5];
  const float* Dp  = (const float*)d_in[6];
  const float* nw  = (const float*)d_in[7];
  const float* oW  = (const float*)d_in[8];
  const float* fW  = (const float*)d_in[9];
  const float* fb  = (const float*)d_in[10];
  const float* lnw = (const float*)d_in[11];
  const float* lnb = (const float*)d_in[12];

  float* ws = (float*)d_ws;
  float* Wc = ws;                                   // 32768 f32
  unsigned short* WpB = (unsigned short*)(ws + 32768); // 4*386*72 = 111168 bf16
  float* x1 = ws + 32768 + 55584;                   // 4194304 f32
  unsigned short* y = (unsigned short*)(x1 + 4194304); // 8388608 bf16

  precomp_wc<<<32, 256, 0, stream>>>(fW, oW, Wc);
  precomp_wpb<<<4, 256, 0, stream>>>(Wp, WpB);
  mamba_dir<<<1024, 256, 0, stream>>>(x, x1, y, WpB, cw, cb, dtb, Al, Dp,
                                      nw, lnw, lnb, Wc, 0);
  combine0<<<512, 256, 0, stream>>>(x, y, fb, x1);
  mamba_dir<<<1024, 256, 0, stream>>>(x, x1, y, WpB, cw, cb, dtb, Al, Dp,
                                      nw, lnw, lnb, Wc, 1);
  combine1<<<512, 256, 0, stream>>>(x1, y, fb + 64, (float*)d_out);
}

// Round 7
// 1213.463 us; speedup vs baseline: 6.0892x; 1.0587x over previous
//
#include <hip/hip_runtime.h>

#define EPSV 1e-5f

__device__ __forceinline__ float sigmoidf_(float x) {
  return 1.f / (1.f + __expf(-x));
}
__device__ __forceinline__ unsigned short f2bf(float f) {
  unsigned int u = __float_as_uint(f);
  u += 0x7fffu + ((u >> 16) & 1u);
  return (unsigned short)(u >> 16);
}
__device__ __forceinline__ float bfu(unsigned short h) {
  union { unsigned int u; float f; } t; t.u = ((unsigned int)h) << 16; return t.f;
}
__device__ __forceinline__ float bflo(unsigned int u) {
  union { unsigned int x; float f; } t; t.x = u << 16; return t.f;
}
__device__ __forceinline__ float bfhi(unsigned int u) {
  union { unsigned int x; float f; } t; t.x = u & 0xffff0000u; return t.f;
}

// ---------------------------------------------------------------------------
// W_comb[i][m][k] = sum_j fusion_W[p][m][d*64+j] * out_W[i][j][k]
// ---------------------------------------------------------------------------
__global__ __launch_bounds__(256) void precomp_wc(
    const float* __restrict__ fW,   // (2,64,128)
    const float* __restrict__ oW,   // (4,64,128)
    float* __restrict__ Wc)         // (4,64,128)
{
  const int bi = blockIdx.x;
  const int i = bi >> 3, mg = bi & 7;
  const int m = (mg << 3) + (threadIdx.x >> 5);
  const int k0 = (threadIdx.x & 31) << 2;
  const int p = i >> 1, d = i & 1;
  const float* fr = fW + p * 8192 + m * 128 + d * 64;
  const float* orow = oW + i * 8192 + k0;
  float a0 = 0.f, a1 = 0.f, a2 = 0.f, a3 = 0.f;
  for (int j = 0; j < 64; ++j) {
    const float f = fr[j];
    const float4 o4 = *(const float4*)(orow + j * 128);
    a0 += f * o4.x; a1 += f * o4.y; a2 += f * o4.z; a3 += f * o4.w;
  }
  float* out = Wc + i * 8192 + m * 128 + k0;
  out[0] = a0; out[1] = a1; out[2] = a2; out[3] = a3;
}

// ---------------------------------------------------------------------------
// in_proj weights -> bf16, padded rows [o][72] (16B-aligned for ds_read_b128)
// ---------------------------------------------------------------------------
__global__ __launch_bounds__(256) void precomp_wpb(
    const float* __restrict__ Wp, unsigned short* __restrict__ WpB)
{
  const int ip = blockIdx.x;
  const float* src = Wp + (size_t)ip * 24704;
  unsigned short* dst = WpB + (size_t)ip * (386 * 72);
  for (int idx = threadIdx.x; idx < 386 * 72; idx += 256) {
    const int o = idx / 72, k = idx - o * 72;
    dst[idx] = (k < 64) ? f2bf(src[o * 64 + k]) : (unsigned short)0;
  }
}

// ---------------------------------------------------------------------------
// One block = one (sequence, direction). 1024 blocks x 512 threads.
// LDS 74.5 KB -> 2 blocks/CU = 16 waves/CU (2x round 6's occupancy); every
// pipeline step's critical path halves. Weights: in_proj bf16 in LDS (once),
// Wc in 16 regs/thread. Live set ~70 VGPR -> (512,4) cap 128 is safe.
// ---------------------------------------------------------------------------
__global__ __launch_bounds__(512, 4) void mamba_dir(
    const float* __restrict__ xin,   // canonical x (4,64,128,128) f32
    const float* __restrict__ x1,    // phase1 input [b][f][t][c] f32
    unsigned short* __restrict__ ybuf, // bf16 [dir][seq][pos][64]
    const unsigned short* __restrict__ WpB, // bf16 padded (4,386,72)
    const float* __restrict__ cwA, const float* __restrict__ cbA,
    const float* __restrict__ dtbA, const float* __restrict__ AlA,
    const float* __restrict__ DpA, const float* __restrict__ nwA,
    const float* __restrict__ lnwA, const float* __restrict__ lnbA,
    const float* __restrict__ WcA,
    int phase)
{
  __shared__ __align__(16) unsigned short sW[386 * 72]; // 55.6 KB bf16 weights
  __shared__ float sZ[8 * 388];   // z(0-127)|xBC(128-383)|dtraw(384-385); y/g overlay 128-255
  __shared__ float sX[8][256];    // conv+silu out; u aliased cols 0-63 pre-conv

  const int tid = threadIdx.x;
  const int blk = blockIdx.x;
  const int seq = blk >> 1, dir = blk & 1;
  const int b = seq >> 7, q = seq & 127;
  const int ip = (phase << 1) + dir;
  const float dtb0 = dtbA[ip * 2], dtb1 = dtbA[ip * 2 + 1];
  const float nA0 = -__expf(AlA[ip * 2]), nA1 = -__expf(AlA[ip * 2 + 1]);
  const float Dp0 = DpA[ip * 2], Dp1 = DpA[ip * 2 + 1];
  const int c256 = tid & 255;                 // conv channel
  const int lh = tid >> 8;                    // conv lt-half
  const float4 cw4 = *(const float4*)(cwA + ip * 1024 + (c256 << 2));
  const float cbias = cbA[ip * 256 + c256];
  float ch0 = 0.f, ch1 = 0.f, ch2 = 0.f;      // conv carry (lh==0 only)
  float S[16];                                // scan state (quarter-row)
  #pragma unroll
  for (int i = 0; i < 16; ++i) S[i] = 0.f;

  // stage in_proj weights into LDS once (coalesced dword copy)
  {
    const unsigned int* srcw =
        (const unsigned int*)(WpB + (size_t)ip * (386 * 72));
    unsigned int* dw = (unsigned int*)sW;
    for (int i = tid; i < 386 * 36; i += 512) dw[i] = srcw[i];
  }
  // Wc into registers: thread owns (m_own = tid>>3, ke = tid&7) -> 16 floats
  const int m_own = tid >> 3, ke = tid & 7;
  float wcr[16];
  {
    const float4* wsrc =
        (const float4*)(WcA + (size_t)ip * 8192 + (m_own << 7) + (ke << 4));
    #pragma unroll
    for (int i = 0; i < 4; ++i) {
      const float4 v = wsrc[i];
      wcr[i * 4 + 0] = v.x; wcr[i * 4 + 1] = v.y;
      wcr[i * 4 + 2] = v.z; wcr[i * 4 + 3] = v.w;
    }
  }
  __syncthreads();

  const size_t sb = phase ? ((size_t)b * 1048576 + (size_t)q * 8192)
                          : ((size_t)b * 1048576 + (size_t)q * 128);
  const float* src = phase ? x1 : xin;

  for (int ck = 0; ck < 16; ++ck) {
    // ---- 1. load 8 pos x 64 ch into sX (u region), 1 elem/thread ----
    if (phase) {
      const int pos = tid >> 6, cl = tid & 63;
      const int st = (ck << 3) + pos, rp = dir ? (127 - st) : st;
      sX[pos][cl] = src[sb + (size_t)rp * 64 + cl];
    } else {
      const int pos = tid & 7, c = tid >> 3;
      const int st = (ck << 3) + pos, rp = dir ? (127 - st) : st;
      sX[pos][c] = src[sb + rp + (size_t)c * 16384];
    }
    __syncthreads();
    // ---- 2. layernorm (full-wave 64-lane reduce) ----
    {
      const int pos = tid >> 6, c = tid & 63;
      const float v = sX[pos][c];
      float sm = v, s2 = v * v;
      sm += __shfl_xor(sm, 1);  s2 += __shfl_xor(s2, 1);
      sm += __shfl_xor(sm, 2);  s2 += __shfl_xor(s2, 2);
      sm += __shfl_xor(sm, 4);  s2 += __shfl_xor(s2, 4);
      sm += __shfl_xor(sm, 8);  s2 += __shfl_xor(s2, 8);
      sm += __shfl_xor(sm, 16); s2 += __shfl_xor(s2, 16);
      sm += __shfl_xor(sm, 32); s2 += __shfl_xor(s2, 32);
      const float mean = sm * (1.f / 64.f);
      const float inv = rsqrtf(s2 * (1.f / 64.f) - mean * mean + EPSV);
      const int lb = (phase << 6) + c;
      sX[pos][c] = (v - mean) * inv * lnwA[lb] + lnbA[lb];
    }
    __syncthreads();
    // ---- 3. in_proj from LDS bf16 weights: one o per thread ----
    {
      const int o = tid;
      if (o < 386) {
        const uint4* wrow = (const uint4*)(&sW[o * 72]);
        float acc[8];
        #pragma unroll
        for (int lt = 0; lt < 8; ++lt) acc[lt] = 0.f;
        #pragma unroll
        for (int k8 = 0; k8 < 8; ++k8) {
          const uint4 wv = wrow[k8];
          const float w0 = bflo(wv.x), w1 = bfhi(wv.x);
          const float w2 = bflo(wv.y), w3 = bfhi(wv.y);
          const float w4 = bflo(wv.z), w5 = bfhi(wv.z);
          const float w6 = bflo(wv.w), w7 = bfhi(wv.w);
          #pragma unroll
          for (int lt = 0; lt < 8; ++lt) {
            const float4 ua = *(const float4*)(&sX[lt][k8 << 3]);
            const float4 ub = *(const float4*)(&sX[lt][(k8 << 3) + 4]);
            acc[lt] += w0 * ua.x + w1 * ua.y + w2 * ua.z + w3 * ua.w +
                       w4 * ub.x + w5 * ub.y + w6 * ub.z + w7 * ub.w;
          }
        }
        #pragma unroll
        for (int lt = 0; lt < 8; ++lt) sZ[lt * 388 + o] = acc[lt];
      }
    }
    __syncthreads();
    // ---- 4. conv(4,causal)+silu; lt 0-3 on lh=0 (reg carry), 4-7 on lh=1 ----
    {
      const int c = c256;
      float a0, a1, a2;
      if (lh == 0) { a0 = ch0; a1 = ch1; a2 = ch2; }
      else {
        a0 = sZ[1 * 388 + 128 + c];
        a1 = sZ[2 * 388 + 128 + c];
        a2 = sZ[3 * 388 + 128 + c];
      }
      const int lt0 = lh << 2;
      #pragma unroll
      for (int l = 0; l < 4; ++l) {
        const int lt = lt0 + l;
        const float a3 = sZ[lt * 388 + 128 + c];
        const float acc = cbias + a0 * cw4.x + a1 * cw4.y + a2 * cw4.z + a3 * cw4.w;
        sX[lt][c] = acc * sigmoidf_(acc);
        a0 = a1; a1 = a2; a2 = a3;
      }
      if (lh == 0) {   // carry for next chunk = raw xBC at lt 5,6,7
        ch0 = sZ[5 * 388 + 128 + c];
        ch1 = sZ[6 * 388 + 128 + c];
        ch2 = sZ[7 * 388 + 128 + c];
      }
    }
    __syncthreads();
    // ---- 5. selective scan: 128 rows x 4 quarter-threads, 16 states each ----
    {
      const int row = tid >> 2, quarter = tid & 3, hh = row >> 6;
      const int boff = 128 + (quarter << 4);
      const float dtbh = hh ? dtb1 : dtb0, nAh = hh ? nA1 : nA0;
      #pragma unroll
      for (int lt = 0; lt < 8; ++lt) {
        const float rawv = sZ[lt * 388 + 384 + hh] + dtbh;
        const float dtv = (rawv > 20.f) ? rawv : log1pf(__expf(rawv));
        const float dA = __expf(dtv * nAh);
        const float dtx = dtv * sX[lt][row];
        const float4* Bp = (const float4*)(&sX[lt][boff]);
        const float4* Cp = (const float4*)(&sX[lt][boff + 64]);
        float yp = 0.f;
        #pragma unroll
        for (int i = 0; i < 4; ++i) {
          const float4 Bv = Bp[i], Cv = Cp[i];
          S[i * 4 + 0] = S[i * 4 + 0] * dA + dtx * Bv.x; yp += S[i * 4 + 0] * Cv.x;
          S[i * 4 + 1] = S[i * 4 + 1] * dA + dtx * Bv.y; yp += S[i * 4 + 1] * Cv.y;
          S[i * 4 + 2] = S[i * 4 + 2] * dA + dtx * Bv.z; yp += S[i * 4 + 2] * Cv.z;
          S[i * 4 + 3] = S[i * 4 + 3] * dA + dtx * Bv.w; yp += S[i * 4 + 3] * Cv.w;
        }
        yp += __shfl_xor(yp, 1);
        yp += __shfl_xor(yp, 2);
        if (quarter == 0) sZ[lt * 388 + 128 + row] = yp;  // y overlays dead xBC
      }
    }
    __syncthreads();
    // ---- 6. gate with silu(z) + rmsnorm (wave = one lt, 2 elems/thread) ----
    {
      const int lt = tid >> 6, kk = tid & 63;
      const int k0 = kk << 1;
      const float2 yv = *(const float2*)(&sZ[lt * 388 + 128 + k0]);
      const float2 zv = *(const float2*)(&sZ[lt * 388 + k0]);
      const float2 xv = *(const float2*)(&sX[lt][k0]);
      const float dp = (kk >= 32) ? Dp1 : Dp0;
      const float g0 = (yv.x + dp * xv.x) * (zv.x * sigmoidf_(zv.x));
      const float g1 = (yv.y + dp * xv.y) * (zv.y * sigmoidf_(zv.y));
      float ssq = g0 * g0 + g1 * g1;
      ssq += __shfl_xor(ssq, 1);
      ssq += __shfl_xor(ssq, 2);
      ssq += __shfl_xor(ssq, 4);
      ssq += __shfl_xor(ssq, 8);
      ssq += __shfl_xor(ssq, 16);
      ssq += __shfl_xor(ssq, 32);
      const float sc = rsqrtf(ssq * (1.f / 128.f) + EPSV);
      const float2 nw2 = *(const float2*)(nwA + ip * 128 + k0);
      float2 gv;
      gv.x = g0 * sc * nw2.x; gv.y = g1 * sc * nw2.y;
      *(float2*)(&sZ[lt * 388 + 128 + k0]) = gv;
    }
    __syncthreads();
    // ---- 7. out-matmul: (m, k-eighth) per thread, shfl reduce over 8 ----
    {
      #pragma unroll
      for (int lt = 0; lt < 8; ++lt) {
        const float4* gp = (const float4*)(&sZ[lt * 388 + 128 + (ke << 4)]);
        float pth = 0.f;
        #pragma unroll
        for (int i = 0; i < 4; ++i) {
          const float4 g4 = gp[i];
          pth += wcr[i * 4 + 0] * g4.x + wcr[i * 4 + 1] * g4.y +
                 wcr[i * 4 + 2] * g4.z + wcr[i * 4 + 3] * g4.w;
        }
        pth += __shfl_xor(pth, 1);
        pth += __shfl_xor(pth, 2);
        pth += __shfl_xor(pth, 4);
        if (ke == 0) {
          const int st = (ck << 3) + lt, rp = dir ? (127 - st) : st;
          ybuf[(((size_t)(dir * 512 + seq) * 128 + rp) << 6) + m_own] = f2bf(pth);
        }
      }
    }
    __syncthreads();
  }
}

// ---------------------------------------------------------------------------
// combine0: x1[b][f][t][c] = x[b][c][t][f] + yf + yb + fb0[c]   (coalesced)
// ---------------------------------------------------------------------------
__global__ __launch_bounds__(256) void combine0(
    const float* __restrict__ x, const unsigned short* __restrict__ ybuf,
    const float* __restrict__ fb, float* __restrict__ x1)
{
  __shared__ float T[64 * 132];
  const int tid = threadIdx.x, blk = blockIdx.x;
  const int b = blk >> 7, t = blk & 127;
  {
    const int c = tid >> 2, f0 = (tid & 3) << 5;
    const float* xp = x + (((size_t)(b * 64 + c) * 128 + t) << 7) + f0;
    float* tp = &T[c * 132 + f0];
    #pragma unroll
    for (int j = 0; j < 8; ++j)
      *(float4*)(tp + (j << 2)) = *(const float4*)(xp + (j << 2));
  }
  __syncthreads();
  {
    const int f = tid >> 1, cb = (tid & 1) << 5;
    const size_t s0 = (size_t)b * 128 + t;
    const unsigned short* yf = ybuf + ((s0 * 128 + f) << 6) + cb;
    const unsigned short* yb = ybuf + (((s0 + 512) * 128 + f) << 6) + cb;
    float* op = x1 + (((size_t)(b * 128 + f) * 128 + t) << 6) + cb;
    #pragma unroll
    for (int j = 0; j < 32; j += 4) {
      float4 v;
      v.x = T[(cb + j + 0) * 132 + f] + bfu(yf[j + 0]) + bfu(yb[j + 0]) + fb[cb + j + 0];
      v.y = T[(cb + j + 1) * 132 + f] + bfu(yf[j + 1]) + bfu(yb[j + 1]) + fb[cb + j + 1];
      v.z = T[(cb + j + 2) * 132 + f] + bfu(yf[j + 2]) + bfu(yb[j + 2]) + fb[cb + j + 2];
      v.w = T[(cb + j + 3) * 132 + f] + bfu(yf[j + 3]) + bfu(yb[j + 3]) + fb[cb + j + 3];
      *(float4*)(op + j) = v;
    }
  }
}

// ---------------------------------------------------------------------------
// combine1: out[b][c][t][f] = x1[b][f][t][c] + yf + yb + fb1[c]  (coalesced)
// ---------------------------------------------------------------------------
__global__ __launch_bounds__(256) void combine1(
    const float* __restrict__ x1, const unsigned short* __restrict__ ybuf,
    const float* __restrict__ fb, float* __restrict__ out)
{
  __shared__ float T[128 * 68];
  const int tid = threadIdx.x, blk = blockIdx.x;
  const int b = blk >> 7, t = blk & 127;
  {
    const int f = tid >> 1, cb = (tid & 1) << 5;
    const size_t s1 = (size_t)b * 128 + f;
    const float* xp = x1 + ((s1 * 128 + t) << 6) + cb;
    const unsigned short* yf = ybuf + ((s1 * 128 + t) << 6) + cb;
    const unsigned short* yb = ybuf + (((s1 + 512) * 128 + t) << 6) + cb;
    float* tp = &T[f * 68 + cb];
    #pragma unroll
    for (int j = 0; j < 32; ++j)
      tp[j] = xp[j] + bfu(yf[j]) + bfu(yb[j]) + fb[cb + j];
  }
  __syncthreads();
  {
    const int c = tid >> 2, f0 = (tid & 3) << 5;
    float* op = out + (((size_t)(b * 64 + c) * 128 + t) << 7) + f0;
    #pragma unroll
    for (int j = 0; j < 32; j += 4) {
      float4 v;
      v.x = T[(f0 + j + 0) * 68 + c];
      v.y = T[(f0 + j + 1) * 68 + c];
      v.z = T[(f0 + j + 2) * 68 + c];
      v.w = T[(f0 + j + 3) * 68 + c];
      *(float4*)(op + j) = v;
    }
  }
}

extern "C" void kernel_launch(void* const* d_in, const int* in_sizes, int n_in,
                              void* d_out, int out_size, void* d_ws, size_t ws_size,
                              hipStream_t stream) {
  const float* x   = (const float*)d_in[0];
  const float* Wp  = (const float*)d_in[1];
  const float* cw  = (const float*)d_in[2];
  const float* cb  = (const float*)d_in[3];
  const float* dtb = (const float*)d_in[4];
  const float* Al  = (const float*)d_in[5];
  const float* Dp  = (const float*)d_in[6];
  const float* nw  = (const float*)d_in[7];
  const float* oW  = (const float*)d_in[8];
  const float* fW  = (const float*)d_in[9];
  const float* fb  = (const float*)d_in[10];
  const float* lnw = (const float*)d_in[11];
  const float* lnb = (const float*)d_in[12];

  float* ws = (float*)d_ws;
  float* Wc = ws;                                   // 32768 f32
  unsigned short* WpB = (unsigned short*)(ws + 32768); // 4*386*72 = 111168 bf16
  float* x1 = ws + 32768 + 55584;                   // 4194304 f32
  unsigned short* y = (unsigned short*)(x1 + 4194304); // 8388608 bf16

  precomp_wc<<<32, 256, 0, stream>>>(fW, oW, Wc);
  precomp_wpb<<<4, 256, 0, stream>>>(Wp, WpB);
  mamba_dir<<<1024, 512, 0, stream>>>(x, x1, y, WpB, cw, cb, dtb, Al, Dp,
                                      nw, lnw, lnb, Wc, 0);
  combine0<<<512, 256, 0, stream>>>(x, y, fb, x1);
  mamba_dir<<<1024, 512, 0, stream>>>(x, x1, y, WpB, cw, cb, dtb, Al, Dp,
                                      nw, lnw, lnb, Wc, 1);
  combine1<<<512, 256, 0, stream>>>(x1, y, fb + 64, (float*)d_out);
}

// Round 8
// 732.261 us; speedup vs baseline: 10.0907x; 1.6571x over previous
//
#include <hip/hip_runtime.h>

#define EPSV 1e-5f

typedef short bf16x8 __attribute__((ext_vector_type(8)));
typedef float f32x4 __attribute__((ext_vector_type(4)));

__device__ __forceinline__ float sigmoidf_(float x) {
  return 1.f / (1.f + __expf(-x));
}
__device__ __forceinline__ unsigned short f2bf(float f) {
  unsigned int u = __float_as_uint(f);
  u += 0x7fffu + ((u >> 16) & 1u);
  return (unsigned short)(u >> 16);
}
__device__ __forceinline__ float bfu(unsigned short h) {
  union { unsigned int u; float f; } t; t.u = ((unsigned int)h) << 16; return t.f;
}
__device__ __forceinline__ float bflo(unsigned int u) {
  union { unsigned int x; float f; } t; t.x = u << 16; return t.f;
}
__device__ __forceinline__ float bfhi(unsigned int u) {
  union { unsigned int x; float f; } t; t.x = u & 0xffff0000u; return t.f;
}

// ---------------------------------------------------------------------------
// W_comb[i][m][k] = sum_j fusion_W[p][m][d*64+j] * out_W[i][j][k]
// ---------------------------------------------------------------------------
__global__ __launch_bounds__(256) void precomp_wc(
    const float* __restrict__ fW,   // (2,64,128)
    const float* __restrict__ oW,   // (4,64,128)
    float* __restrict__ Wc)         // (4,64,128)
{
  const int bi = blockIdx.x;
  const int i = bi >> 3, mg = bi & 7;
  const int m = (mg << 3) + (threadIdx.x >> 5);
  const int k0 = (threadIdx.x & 31) << 2;
  const int p = i >> 1, d = i & 1;
  const float* fr = fW + p * 8192 + m * 128 + d * 64;
  const float* orow = oW + i * 8192 + k0;
  float a0 = 0.f, a1 = 0.f, a2 = 0.f, a3 = 0.f;
  for (int j = 0; j < 64; ++j) {
    const float f = fr[j];
    const float4 o4 = *(const float4*)(orow + j * 128);
    a0 += f * o4.x; a1 += f * o4.y; a2 += f * o4.z; a3 += f * o4.w;
  }
  float* out = Wc + i * 8192 + m * 128 + k0;
  out[0] = a0; out[1] = a1; out[2] = a2; out[3] = a3;
}

// ---------------------------------------------------------------------------
// in_proj weights -> bf16 [400][72] rows (rows 386-399 zero; k>=64 zero).
// Row stride 72 shorts: 16B-aligned fragments, 2-way-free LDS banks.
// ---------------------------------------------------------------------------
__global__ __launch_bounds__(256) void precomp_wpb(
    const float* __restrict__ Wp, unsigned short* __restrict__ WpB)
{
  const int ip = blockIdx.x;
  const float* src = Wp + (size_t)ip * 24704;
  unsigned short* dst = WpB + (size_t)ip * (400 * 72);
  for (int idx = threadIdx.x; idx < 400 * 72; idx += 256) {
    const int o = idx / 72, k = idx - o * 72;
    dst[idx] = (o < 386 && k < 64) ? f2bf(src[o * 64 + k]) : (unsigned short)0;
  }
}

// ---------------------------------------------------------------------------
// One block = one (sequence, direction). 1024 blocks x 512 threads (8 waves).
// in_proj via MFMA 16x16x32 bf16 (M=16, 8 valid token rows, 25 N-tiles, K=64).
// dt/dA precomputed once per chunk. LDS 78.8 KB -> 2 blocks/CU.
// ---------------------------------------------------------------------------
__global__ __launch_bounds__(512, 4) void mamba_dir(
    const float* __restrict__ xin,   // canonical x (4,64,128,128) f32
    const float* __restrict__ x1,    // phase1 input [b][f][t][c] f32
    unsigned short* __restrict__ ybuf, // bf16 [dir][seq][pos][64]
    const unsigned short* __restrict__ WpB, // bf16 (4,400,72)
    const float* __restrict__ cwA, const float* __restrict__ cbA,
    const float* __restrict__ dtbA, const float* __restrict__ AlA,
    const float* __restrict__ DpA, const float* __restrict__ nwA,
    const float* __restrict__ lnwA, const float* __restrict__ lnbA,
    const float* __restrict__ WcA,
    int phase)
{
  __shared__ __align__(16) unsigned short sW[400 * 72]; // 57.6 KB weights (B)
  __shared__ __align__(16) unsigned short sU[16 * 72];  // 2.25 KB LN'd u (A)
  __shared__ __align__(16) unsigned short sZb[8 * 136]; // 2.2 KB z (bf16)
  __shared__ __align__(16) float sZx[8 * 260];          // 8.3 KB xBC / y / g
  __shared__ float sX[8][256];                          // 8 KB conv+silu out
  __shared__ float sDtRaw[8][2], sDtv[8][2], sDa[8][2];

  const int tid = threadIdx.x;
  const int blk = blockIdx.x;
  const int seq = blk >> 1, dir = blk & 1;
  const int b = seq >> 7, q = seq & 127;
  const int ip = (phase << 1) + dir;
  const float dtb0 = dtbA[ip * 2], dtb1 = dtbA[ip * 2 + 1];
  const float nA0 = -__expf(AlA[ip * 2]), nA1 = -__expf(AlA[ip * 2 + 1]);
  const float Dp0 = DpA[ip * 2], Dp1 = DpA[ip * 2 + 1];
  const int c256 = tid & 255;                 // conv channel
  const int lh = tid >> 8;                    // conv lt-half
  const float4 cw4 = *(const float4*)(cwA + ip * 1024 + (c256 << 2));
  const float cbias = cbA[ip * 256 + c256];
  float ch0 = 0.f, ch1 = 0.f, ch2 = 0.f;      // conv carry (lh==0 only)
  float S[16];                                // scan state (quarter-row)
  #pragma unroll
  for (int i = 0; i < 16; ++i) S[i] = 0.f;

  // stage weights + zero sU once
  {
    const unsigned int* srcw =
        (const unsigned int*)(WpB + (size_t)ip * (400 * 72));
    unsigned int* dw = (unsigned int*)sW;
    for (int i = tid; i < 400 * 36; i += 512) dw[i] = srcw[i];
    unsigned int* du = (unsigned int*)sU;
    for (int i = tid; i < 16 * 36; i += 512) du[i] = 0u;
  }
  // Wc into registers: thread owns (m_own = tid>>3, ke = tid&7) -> 16 floats
  const int m_own = tid >> 3, ke = tid & 7;
  float wcr[16];
  {
    const float4* wsrc =
        (const float4*)(WcA + (size_t)ip * 8192 + (m_own << 7) + (ke << 4));
    #pragma unroll
    for (int i = 0; i < 4; ++i) {
      const float4 v = wsrc[i];
      wcr[i * 4 + 0] = v.x; wcr[i * 4 + 1] = v.y;
      wcr[i * 4 + 2] = v.z; wcr[i * 4 + 3] = v.w;
    }
  }
  __syncthreads();

  const size_t sb = phase ? ((size_t)b * 1048576 + (size_t)q * 8192)
                          : ((size_t)b * 1048576 + (size_t)q * 128);
  const float* src = phase ? x1 : xin;

  for (int ck = 0; ck < 16; ++ck) {
    // ---- 1. load 8 pos x 64 ch into sX, 1 elem/thread ----
    if (phase) {
      const int pos = tid >> 6, cl = tid & 63;
      const int st = (ck << 3) + pos, rp = dir ? (127 - st) : st;
      sX[pos][cl] = src[sb + (size_t)rp * 64 + cl];
    } else {
      const int pos = tid & 7, c = tid >> 3;
      const int st = (ck << 3) + pos, rp = dir ? (127 - st) : st;
      sX[pos][c] = src[sb + rp + (size_t)c * 16384];
    }
    __syncthreads();
    // ---- 2. layernorm -> bf16 A-operand staging ----
    {
      const int pos = tid >> 6, c = tid & 63;
      const float v = sX[pos][c];
      float sm = v, s2 = v * v;
      sm += __shfl_xor(sm, 1);  s2 += __shfl_xor(s2, 1);
      sm += __shfl_xor(sm, 2);  s2 += __shfl_xor(s2, 2);
      sm += __shfl_xor(sm, 4);  s2 += __shfl_xor(s2, 4);
      sm += __shfl_xor(sm, 8);  s2 += __shfl_xor(s2, 8);
      sm += __shfl_xor(sm, 16); s2 += __shfl_xor(s2, 16);
      sm += __shfl_xor(sm, 32); s2 += __shfl_xor(s2, 32);
      const float mean = sm * (1.f / 64.f);
      const float inv = rsqrtf(s2 * (1.f / 64.f) - mean * mean + EPSV);
      const int lb = (phase << 6) + c;
      sU[pos * 72 + c] = f2bf((v - mean) * inv * lnwA[lb] + lnbA[lb]);
    }
    __syncthreads();
    // ---- 3. in_proj via MFMA: 25 N-tiles x 2 K-steps over 8 waves ----
    {
      const int wave = tid >> 6, lane = tid & 63;
      const int col = lane & 15, quad = lane >> 4;
      const bf16x8 a0 = *(const bf16x8*)(&sU[col * 72 + quad * 8]);
      const bf16x8 a1 = *(const bf16x8*)(&sU[col * 72 + quad * 8 + 32]);
      for (int tile = wave; tile < 25; tile += 8) {
        const unsigned short* wb = &sW[(tile * 16 + col) * 72 + quad * 8];
        const bf16x8 b0 = *(const bf16x8*)(wb);
        const bf16x8 b1 = *(const bf16x8*)(wb + 32);
        f32x4 d = {0.f, 0.f, 0.f, 0.f};
        d = __builtin_amdgcn_mfma_f32_16x16x32_bf16(a0, b0, d, 0, 0, 0);
        d = __builtin_amdgcn_mfma_f32_16x16x32_bf16(a1, b1, d, 0, 0, 0);
        if (quad < 2) {                 // valid token rows 0-7
          const int o = (tile << 4) + col;
          if (tile < 8) {               // z -> bf16
            #pragma unroll
            for (int r = 0; r < 4; ++r)
              sZb[(quad * 4 + r) * 136 + o] = f2bf(d[r]);
          } else if (tile < 24) {       // xBC -> f32
            #pragma unroll
            for (int r = 0; r < 4; ++r)
              sZx[(quad * 4 + r) * 260 + (o - 128)] = d[r];
          } else if (col < 2) {         // dt raw (o = 384,385)
            #pragma unroll
            for (int r = 0; r < 4; ++r)
              sDtRaw[quad * 4 + r][col] = d[r];
          }
        }
      }
    }
    __syncthreads();
    // ---- 4. conv(4,causal)+silu; dt/dA precompute by 16 threads ----
    {
      const int c = c256;
      float a0c, a1c, a2c;
      if (lh == 0) { a0c = ch0; a1c = ch1; a2c = ch2; }
      else {
        a0c = sZx[1 * 260 + c];
        a1c = sZx[2 * 260 + c];
        a2c = sZx[3 * 260 + c];
      }
      const int lt0 = lh << 2;
      #pragma unroll
      for (int l = 0; l < 4; ++l) {
        const int lt = lt0 + l;
        const float a3 = sZx[lt * 260 + c];
        const float acc = cbias + a0c * cw4.x + a1c * cw4.y + a2c * cw4.z + a3 * cw4.w;
        sX[lt][c] = acc * sigmoidf_(acc);
        a0c = a1c; a1c = a2c; a2c = a3;
      }
      if (lh == 0) {   // carry = raw xBC at lt 5,6,7
        ch0 = sZx[5 * 260 + c];
        ch1 = sZx[6 * 260 + c];
        ch2 = sZx[7 * 260 + c];
      }
      if (tid < 16) {
        const int lt = tid >> 1, hh = tid & 1;
        const float rawv = sDtRaw[lt][hh] + (hh ? dtb1 : dtb0);
        const float dtv = (rawv > 20.f) ? rawv : log1pf(__expf(rawv));
        sDtv[lt][hh] = dtv;
        sDa[lt][hh] = __expf(dtv * (hh ? nA1 : nA0));
      }
    }
    __syncthreads();
    // ---- 5. selective scan: 128 rows x 4 quarters, 16 states each ----
    {
      const int row = tid >> 2, quarter = tid & 3, hh = row >> 6;
      const int boff = 128 + (quarter << 4);
      #pragma unroll
      for (int lt = 0; lt < 8; ++lt) {
        const float dtv = sDtv[lt][hh];
        const float dA = sDa[lt][hh];
        const float dtx = dtv * sX[lt][row];
        const float4* Bp = (const float4*)(&sX[lt][boff]);
        const float4* Cp = (const float4*)(&sX[lt][boff + 64]);
        float yp = 0.f;
        #pragma unroll
        for (int i = 0; i < 4; ++i) {
          const float4 Bv = Bp[i], Cv = Cp[i];
          S[i * 4 + 0] = S[i * 4 + 0] * dA + dtx * Bv.x; yp += S[i * 4 + 0] * Cv.x;
          S[i * 4 + 1] = S[i * 4 + 1] * dA + dtx * Bv.y; yp += S[i * 4 + 1] * Cv.y;
          S[i * 4 + 2] = S[i * 4 + 2] * dA + dtx * Bv.z; yp += S[i * 4 + 2] * Cv.z;
          S[i * 4 + 3] = S[i * 4 + 3] * dA + dtx * Bv.w; yp += S[i * 4 + 3] * Cv.w;
        }
        yp += __shfl_xor(yp, 1);
        yp += __shfl_xor(yp, 2);
        if (quarter == 0) sZx[lt * 260 + row] = yp;   // y into dead xBC x-region
      }
    }
    __syncthreads();
    // ---- 6. gate with silu(z) + rmsnorm (wave = one lt, 2 elems/thread) ----
    {
      const int lt = tid >> 6, kk = tid & 63, k0 = kk << 1;
      const float2 yv = *(const float2*)(&sZx[lt * 260 + k0]);
      const unsigned int zp = *(const unsigned int*)(&sZb[lt * 136 + k0]);
      const float z0 = bflo(zp), z1 = bfhi(zp);
      const float2 xv = *(const float2*)(&sX[lt][k0]);
      const float dp = (kk >= 32) ? Dp1 : Dp0;
      const float g0 = (yv.x + dp * xv.x) * (z0 * sigmoidf_(z0));
      const float g1 = (yv.y + dp * xv.y) * (z1 * sigmoidf_(z1));
      float ssq = g0 * g0 + g1 * g1;
      ssq += __shfl_xor(ssq, 1);
      ssq += __shfl_xor(ssq, 2);
      ssq += __shfl_xor(ssq, 4);
      ssq += __shfl_xor(ssq, 8);
      ssq += __shfl_xor(ssq, 16);
      ssq += __shfl_xor(ssq, 32);
      const float sc = rsqrtf(ssq * (1.f / 128.f) + EPSV);
      const float2 nw2 = *(const float2*)(nwA + ip * 128 + k0);
      float2 gv;
      gv.x = g0 * sc * nw2.x; gv.y = g1 * sc * nw2.y;
      *(float2*)(&sZx[lt * 260 + k0]) = gv;
    }
    __syncthreads();
    // ---- 7. out-matmul: (m, k-eighth)/thread, shfl reduce (no barrier:
    //         next write to sZx is step 3', two barriers away) ----
    {
      #pragma unroll
      for (int lt = 0; lt < 8; ++lt) {
        const float4* gp = (const float4*)(&sZx[lt * 260 + (ke << 4)]);
        float pth = 0.f;
        #pragma unroll
        for (int i = 0; i < 4; ++i) {
          const float4 g4 = gp[i];
          pth += wcr[i * 4 + 0] * g4.x + wcr[i * 4 + 1] * g4.y +
                 wcr[i * 4 + 2] * g4.z + wcr[i * 4 + 3] * g4.w;
        }
        pth += __shfl_xor(pth, 1);
        pth += __shfl_xor(pth, 2);
        pth += __shfl_xor(pth, 4);
        if (ke == 0) {
          const int st = (ck << 3) + lt, rp = dir ? (127 - st) : st;
          ybuf[(((size_t)(dir * 512 + seq) * 128 + rp) << 6) + m_own] = f2bf(pth);
        }
      }
    }
  }
}

// ---------------------------------------------------------------------------
// combine0: x1[b][f][t][c] = x[b][c][t][f] + yf + yb + fb0[c]   (coalesced)
// ---------------------------------------------------------------------------
__global__ __launch_bounds__(256) void combine0(
    const float* __restrict__ x, const unsigned short* __restrict__ ybuf,
    const float* __restrict__ fb, float* __restrict__ x1)
{
  __shared__ float T[64 * 132];
  const int tid = threadIdx.x, blk = blockIdx.x;
  const int b = blk >> 7, t = blk & 127;
  {
    const int c = tid >> 2, f0 = (tid & 3) << 5;
    const float* xp = x + (((size_t)(b * 64 + c) * 128 + t) << 7) + f0;
    float* tp = &T[c * 132 + f0];
    #pragma unroll
    for (int j = 0; j < 8; ++j)
      *(float4*)(tp + (j << 2)) = *(const float4*)(xp + (j << 2));
  }
  __syncthreads();
  {
    const int f = tid >> 1, cb = (tid & 1) << 5;
    const size_t s0 = (size_t)b * 128 + t;
    const unsigned short* yf = ybuf + ((s0 * 128 + f) << 6) + cb;
    const unsigned short* yb = ybuf + (((s0 + 512) * 128 + f) << 6) + cb;
    float* op = x1 + (((size_t)(b * 128 + f) * 128 + t) << 6) + cb;
    #pragma unroll
    for (int j = 0; j < 32; j += 4) {
      float4 v;
      v.x = T[(cb + j + 0) * 132 + f] + bfu(yf[j + 0]) + bfu(yb[j + 0]) + fb[cb + j + 0];
      v.y = T[(cb + j + 1) * 132 + f] + bfu(yf[j + 1]) + bfu(yb[j + 1]) + fb[cb + j + 1];
      v.z = T[(cb + j + 2) * 132 + f] + bfu(yf[j + 2]) + bfu(yb[j + 2]) + fb[cb + j + 2];
      v.w = T[(cb + j + 3) * 132 + f] + bfu(yf[j + 3]) + bfu(yb[j + 3]) + fb[cb + j + 3];
      *(float4*)(op + j) = v;
    }
  }
}

// ---------------------------------------------------------------------------
// combine1: out[b][c][t][f] = x1[b][f][t][c] + yf + yb + fb1[c]  (coalesced)
// ---------------------------------------------------------------------------
__global__ __launch_bounds__(256) void combine1(
    const float* __restrict__ x1, const unsigned short* __restrict__ ybuf,
    const float* __restrict__ fb, float* __restrict__ out)
{
  __shared__ float T[128 * 68];
  const int tid = threadIdx.x, blk = blockIdx.x;
  const int b = blk >> 7, t = blk & 127;
  {
    const int f = tid >> 1, cb = (tid & 1) << 5;
    const size_t s1 = (size_t)b * 128 + f;
    const float* xp = x1 + ((s1 * 128 + t) << 6) + cb;
    const unsigned short* yf = ybuf + ((s1 * 128 + t) << 6) + cb;
    const unsigned short* yb = ybuf + (((s1 + 512) * 128 + t) << 6) + cb;
    float* tp = &T[f * 68 + cb];
    #pragma unroll
    for (int j = 0; j < 32; ++j)
      tp[j] = xp[j] + bfu(yf[j]) + bfu(yb[j]) + fb[cb + j];
  }
  __syncthreads();
  {
    const int c = tid >> 2, f0 = (tid & 3) << 5;
    float* op = out + (((size_t)(b * 64 + c) * 128 + t) << 7) + f0;
    #pragma unroll
    for (int j = 0; j < 32; j += 4) {
      float4 v;
      v.x = T[(f0 + j + 0) * 68 + c];
      v.y = T[(f0 + j + 1) * 68 + c];
      v.z = T[(f0 + j + 2) * 68 + c];
      v.w = T[(f0 + j + 3) * 68 + c];
      *(float4*)(op + j) = v;
    }
  }
}

extern "C" void kernel_launch(void* const* d_in, const int* in_sizes, int n_in,
                              void* d_out, int out_size, void* d_ws, size_t ws_size,
                              hipStream_t stream) {
  const float* x   = (const float*)d_in[0];
  const float* Wp  = (const float*)d_in[1];
  const float* cw  = (const float*)d_in[2];
  const float* cb  = (const float*)d_in[3];
  const float* dtb = (const float*)d_in[4];
  const float* Al  = (const float*)d_in[5];
  const float* Dp  = (const float*)d_in[6];
  const float* nw  = (const float*)d_in[7];
  const float* oW  = (const float*)d_in[8];
  const float* fW  = (const float*)d_in[9];
  const float* fb  = (const float*)d_in[10];
  const float* lnw = (const float*)d_in[11];
  const float* lnb = (const float*)d_in[12];

  float* ws = (float*)d_ws;
  float* Wc = ws;                                   // 32768 f32
  unsigned short* WpB = (unsigned short*)(ws + 32768); // 4*400*72 = 115200 bf16
  float* x1 = ws + 32768 + 57600;                   // 4194304 f32
  unsigned short* y = (unsigned short*)(x1 + 4194304); // 8388608 bf16

  precomp_wc<<<32, 256, 0, stream>>>(fW, oW, Wc);
  precomp_wpb<<<4, 256, 0, stream>>>(Wp, WpB);
  mamba_dir<<<1024, 512, 0, stream>>>(x, x1, y, WpB, cw, cb, dtb, Al, Dp,
                                      nw, lnw, lnb, Wc, 0);
  combine0<<<512, 256, 0, stream>>>(x, y, fb, x1);
  mamba_dir<<<1024, 512, 0, stream>>>(x, x1, y, WpB, cw, cb, dtb, Al, Dp,
                                      nw, lnw, lnb, Wc, 1);
  combine1<<<512, 256, 0, stream>>>(x1, y, fb + 64, (float*)d_out);
}

// Round 9
// 717.510 us; speedup vs baseline: 10.2981x; 1.0206x over previous
//
#include <hip/hip_runtime.h>

#define EPSV 1e-5f

typedef short bf16x8 __attribute__((ext_vector_type(8)));
typedef float f32x4 __attribute__((ext_vector_type(4)));

__device__ __forceinline__ float sigmoidf_(float x) {
  return 1.f / (1.f + __expf(-x));
}
__device__ __forceinline__ unsigned short f2bf(float f) {
  unsigned int u = __float_as_uint(f);
  u += 0x7fffu + ((u >> 16) & 1u);
  return (unsigned short)(u >> 16);
}
__device__ __forceinline__ float bfu(unsigned short h) {
  union { unsigned int u; float f; } t; t.u = ((unsigned int)h) << 16; return t.f;
}
__device__ __forceinline__ float bflo(unsigned int u) {
  union { unsigned int x; float f; } t; t.x = u << 16; return t.f;
}
__device__ __forceinline__ float bfhi(unsigned int u) {
  union { unsigned int x; float f; } t; t.x = u & 0xffff0000u; return t.f;
}

// ---------------------------------------------------------------------------
// W_comb[i][m][k] = sum_j fusion_W[p][m][d*64+j] * out_W[i][j][k]
// ---------------------------------------------------------------------------
__global__ __launch_bounds__(256) void precomp_wc(
    const float* __restrict__ fW,   // (2,64,128)
    const float* __restrict__ oW,   // (4,64,128)
    float* __restrict__ Wc)         // (4,64,128)
{
  const int bi = blockIdx.x;
  const int i = bi >> 3, mg = bi & 7;
  const int m = (mg << 3) + (threadIdx.x >> 5);
  const int k0 = (threadIdx.x & 31) << 2;
  const int p = i >> 1, d = i & 1;
  const float* fr = fW + p * 8192 + m * 128 + d * 64;
  const float* orow = oW + i * 8192 + k0;
  float a0 = 0.f, a1 = 0.f, a2 = 0.f, a3 = 0.f;
  for (int j = 0; j < 64; ++j) {
    const float f = fr[j];
    const float4 o4 = *(const float4*)(orow + j * 128);
    a0 += f * o4.x; a1 += f * o4.y; a2 += f * o4.z; a3 += f * o4.w;
  }
  float* out = Wc + i * 8192 + m * 128 + k0;
  out[0] = a0; out[1] = a1; out[2] = a2; out[3] = a3;
}

// ---------------------------------------------------------------------------
// in_proj weights -> bf16 in MFMA B-fragment order:
// WpF[ip][tile][h][lane][8] with lane=(quad<<4)|col:
//   element j = Wp[ip][o = tile*16+col][k = h*32 + quad*8 + j]  (o>=386 -> 0)
// A wave's fragment load = one coalesced 1KB global_load_dwordx4.
// ---------------------------------------------------------------------------
__global__ __launch_bounds__(256) void precomp_wpf(
    const float* __restrict__ Wp, unsigned short* __restrict__ WpF)
{
  const int ip = blockIdx.x;
  const float* src = Wp + (size_t)ip * 24704;
  unsigned short* dst = WpF + (size_t)ip * 25600;
  for (int idx = threadIdx.x; idx < 25600; idx += 256) {
    const int tile = idx >> 10;
    const int rem = idx & 1023;
    const int h = rem >> 9;
    const int lane = (rem >> 3) & 63;
    const int j = idx & 7;
    const int col = lane & 15, quad = lane >> 4;
    const int o = tile * 16 + col;
    const int k = h * 32 + quad * 8 + j;
    dst[idx] = (o < 386) ? f2bf(src[o * 64 + k]) : (unsigned short)0;
  }
}

// ---------------------------------------------------------------------------
// One block = one (sequence, direction). 1024 blocks x 512 threads (8 waves).
// in_proj via MFMA with B fragments streamed from global (L2-resident, no
// LDS staging). LDS 21.3 KB -> ALL 4 blocks/CU co-resident (32 waves/CU at
// VGPR=64), single occupancy round, 4-block barrier overlap.
// ---------------------------------------------------------------------------
__global__ __launch_bounds__(512, 4) void mamba_dir(
    const float* __restrict__ xin,   // canonical x (4,64,128,128) f32
    const float* __restrict__ x1,    // phase1 input [b][f][t][c] f32
    unsigned short* __restrict__ ybuf, // bf16 [dir][seq][pos][64]
    const unsigned short* __restrict__ WpF, // bf16 fragments (4,25600)
    const float* __restrict__ cwA, const float* __restrict__ cbA,
    const float* __restrict__ dtbA, const float* __restrict__ AlA,
    const float* __restrict__ DpA, const float* __restrict__ nwA,
    const float* __restrict__ lnwA, const float* __restrict__ lnbA,
    const float* __restrict__ WcA,
    int phase)
{
  __shared__ __align__(16) unsigned short sU[16 * 72];  // 2.25 KB LN'd u (A)
  __shared__ __align__(16) unsigned short sZb[8 * 136]; // 2.2 KB z (bf16)
  __shared__ __align__(16) float sZx[8 * 260];          // 8.3 KB xBC / y / g
  __shared__ float sX[8][256];                          // 8 KB conv+silu out
  __shared__ float sDtRaw[8][2], sDtv[8][2], sDa[8][2];

  const int tid = threadIdx.x;
  const int blk = blockIdx.x;
  const int seq = blk >> 1, dir = blk & 1;
  const int b = seq >> 7, q = seq & 127;
  const int ip = (phase << 1) + dir;
  const float dtb0 = dtbA[ip * 2], dtb1 = dtbA[ip * 2 + 1];
  const float nA0 = -__expf(AlA[ip * 2]), nA1 = -__expf(AlA[ip * 2 + 1]);
  const float Dp0 = DpA[ip * 2], Dp1 = DpA[ip * 2 + 1];
  const int c256 = tid & 255;                 // conv channel
  const int lh = tid >> 8;                    // conv lt-half
  const float4 cw4 = *(const float4*)(cwA + ip * 1024 + (c256 << 2));
  const float cbias = cbA[ip * 256 + c256];
  float ch0 = 0.f, ch1 = 0.f, ch2 = 0.f;      // conv carry (lh==0 only)
  float S[16];                                // scan state (quarter-row)
  #pragma unroll
  for (int i = 0; i < 16; ++i) S[i] = 0.f;

  // zero sU once (rows 8-15 stay zero; rows 0-7 rewritten each chunk)
  {
    unsigned int* du = (unsigned int*)sU;
    for (int i = tid; i < 16 * 36; i += 512) du[i] = 0u;
  }
  // Wc into registers: thread owns (m_own = tid>>3, ke = tid&7) -> 16 floats
  const int m_own = tid >> 3, ke = tid & 7;
  float wcr[16];
  {
    const float4* wsrc =
        (const float4*)(WcA + (size_t)ip * 8192 + (m_own << 7) + (ke << 4));
    #pragma unroll
    for (int i = 0; i < 4; ++i) {
      const float4 v = wsrc[i];
      wcr[i * 4 + 0] = v.x; wcr[i * 4 + 1] = v.y;
      wcr[i * 4 + 2] = v.z; wcr[i * 4 + 3] = v.w;
    }
  }
  const unsigned short* wf = WpF + (size_t)ip * 25600;
  __syncthreads();

  const size_t sb = phase ? ((size_t)b * 1048576 + (size_t)q * 8192)
                          : ((size_t)b * 1048576 + (size_t)q * 128);
  const float* src = phase ? x1 : xin;

  for (int ck = 0; ck < 16; ++ck) {
    // ---- 1. load 8 pos x 64 ch into sX, 1 elem/thread ----
    if (phase) {
      const int pos = tid >> 6, cl = tid & 63;
      const int st = (ck << 3) + pos, rp = dir ? (127 - st) : st;
      sX[pos][cl] = src[sb + (size_t)rp * 64 + cl];
    } else {
      const int pos = tid & 7, c = tid >> 3;
      const int st = (ck << 3) + pos, rp = dir ? (127 - st) : st;
      sX[pos][c] = src[sb + rp + (size_t)c * 16384];
    }
    __syncthreads();
    // ---- 2. layernorm -> bf16 A-operand staging ----
    {
      const int pos = tid >> 6, c = tid & 63;
      const float v = sX[pos][c];
      float sm = v, s2 = v * v;
      sm += __shfl_xor(sm, 1);  s2 += __shfl_xor(s2, 1);
      sm += __shfl_xor(sm, 2);  s2 += __shfl_xor(s2, 2);
      sm += __shfl_xor(sm, 4);  s2 += __shfl_xor(s2, 4);
      sm += __shfl_xor(sm, 8);  s2 += __shfl_xor(s2, 8);
      sm += __shfl_xor(sm, 16); s2 += __shfl_xor(s2, 16);
      sm += __shfl_xor(sm, 32); s2 += __shfl_xor(s2, 32);
      const float mean = sm * (1.f / 64.f);
      const float inv = rsqrtf(s2 * (1.f / 64.f) - mean * mean + EPSV);
      const int lb = (phase << 6) + c;
      sU[pos * 72 + c] = f2bf((v - mean) * inv * lnwA[lb] + lnbA[lb]);
    }
    __syncthreads();
    // ---- 3. in_proj via MFMA; B fragments streamed from global/L2 ----
    {
      const int wave = tid >> 6, lane = tid & 63;
      const int col = lane & 15, quad = lane >> 4;
      const bf16x8 a0 = *(const bf16x8*)(&sU[col * 72 + quad * 8]);
      const bf16x8 a1 = *(const bf16x8*)(&sU[col * 72 + quad * 8 + 32]);
      for (int tile = wave; tile < 25; tile += 8) {
        const unsigned short* wt = wf + (tile << 10) + (lane << 3);
        const bf16x8 b0 = *(const bf16x8*)(wt);
        const bf16x8 b1 = *(const bf16x8*)(wt + 512);
        f32x4 d = {0.f, 0.f, 0.f, 0.f};
        d = __builtin_amdgcn_mfma_f32_16x16x32_bf16(a0, b0, d, 0, 0, 0);
        d = __builtin_amdgcn_mfma_f32_16x16x32_bf16(a1, b1, d, 0, 0, 0);
        if (quad < 2) {                 // valid token rows 0-7
          const int o = (tile << 4) + col;
          if (tile < 8) {               // z -> bf16
            #pragma unroll
            for (int r = 0; r < 4; ++r)
              sZb[(quad * 4 + r) * 136 + o] = f2bf(d[r]);
          } else if (tile < 24) {       // xBC -> f32
            #pragma unroll
            for (int r = 0; r < 4; ++r)
              sZx[(quad * 4 + r) * 260 + (o - 128)] = d[r];
          } else if (col < 2) {         // dt raw (o = 384,385)
            #pragma unroll
            for (int r = 0; r < 4; ++r)
              sDtRaw[quad * 4 + r][col] = d[r];
          }
        }
      }
    }
    __syncthreads();
    // ---- 4. conv(4,causal)+silu; dt/dA precompute by 16 threads ----
    {
      const int c = c256;
      float a0c, a1c, a2c;
      if (lh == 0) { a0c = ch0; a1c = ch1; a2c = ch2; }
      else {
        a0c = sZx[1 * 260 + c];
        a1c = sZx[2 * 260 + c];
        a2c = sZx[3 * 260 + c];
      }
      const int lt0 = lh << 2;
      #pragma unroll
      for (int l = 0; l < 4; ++l) {
        const int lt = lt0 + l;
        const float a3 = sZx[lt * 260 + c];
        const float acc = cbias + a0c * cw4.x + a1c * cw4.y + a2c * cw4.z + a3 * cw4.w;
        sX[lt][c] = acc * sigmoidf_(acc);
        a0c = a1c; a1c = a2c; a2c = a3;
      }
      if (lh == 0) {   // carry = raw xBC at lt 5,6,7
        ch0 = sZx[5 * 260 + c];
        ch1 = sZx[6 * 260 + c];
        ch2 = sZx[7 * 260 + c];
      }
      if (tid < 16) {
        const int lt = tid >> 1, hh = tid & 1;
        const float rawv = sDtRaw[lt][hh] + (hh ? dtb1 : dtb0);
        const float dtv = (rawv > 20.f) ? rawv : log1pf(__expf(rawv));
        sDtv[lt][hh] = dtv;
        sDa[lt][hh] = __expf(dtv * (hh ? nA1 : nA0));
      }
    }
    __syncthreads();
    // ---- 5. selective scan: 128 rows x 4 quarters, 16 states each ----
    {
      const int row = tid >> 2, quarter = tid & 3, hh = row >> 6;
      const int boff = 128 + (quarter << 4);
      #pragma unroll
      for (int lt = 0; lt < 8; ++lt) {
        const float dtv = sDtv[lt][hh];
        const float dA = sDa[lt][hh];
        const float dtx = dtv * sX[lt][row];
        const float4* Bp = (const float4*)(&sX[lt][boff]);
        const float4* Cp = (const float4*)(&sX[lt][boff + 64]);
        float yp = 0.f;
        #pragma unroll
        for (int i = 0; i < 4; ++i) {
          const float4 Bv = Bp[i], Cv = Cp[i];
          S[i * 4 + 0] = S[i * 4 + 0] * dA + dtx * Bv.x; yp += S[i * 4 + 0] * Cv.x;
          S[i * 4 + 1] = S[i * 4 + 1] * dA + dtx * Bv.y; yp += S[i * 4 + 1] * Cv.y;
          S[i * 4 + 2] = S[i * 4 + 2] * dA + dtx * Bv.z; yp += S[i * 4 + 2] * Cv.z;
          S[i * 4 + 3] = S[i * 4 + 3] * dA + dtx * Bv.w; yp += S[i * 4 + 3] * Cv.w;
        }
        yp += __shfl_xor(yp, 1);
        yp += __shfl_xor(yp, 2);
        if (quarter == 0) sZx[lt * 260 + row] = yp;   // y into dead xBC x-region
      }
    }
    __syncthreads();
    // ---- 6. gate with silu(z) + rmsnorm (wave = one lt, 2 elems/thread) ----
    {
      const int lt = tid >> 6, kk = tid & 63, k0 = kk << 1;
      const float2 yv = *(const float2*)(&sZx[lt * 260 + k0]);
      const unsigned int zp = *(const unsigned int*)(&sZb[lt * 136 + k0]);
      const float z0 = bflo(zp), z1 = bfhi(zp);
      const float2 xv = *(const float2*)(&sX[lt][k0]);
      const float dp = (kk >= 32) ? Dp1 : Dp0;
      const float g0 = (yv.x + dp * xv.x) * (z0 * sigmoidf_(z0));
      const float g1 = (yv.y + dp * xv.y) * (z1 * sigmoidf_(z1));
      float ssq = g0 * g0 + g1 * g1;
      ssq += __shfl_xor(ssq, 1);
      ssq += __shfl_xor(ssq, 2);
      ssq += __shfl_xor(ssq, 4);
      ssq += __shfl_xor(ssq, 8);
      ssq += __shfl_xor(ssq, 16);
      ssq += __shfl_xor(ssq, 32);
      const float sc = rsqrtf(ssq * (1.f / 128.f) + EPSV);
      const float2 nw2 = *(const float2*)(nwA + ip * 128 + k0);
      float2 gv;
      gv.x = g0 * sc * nw2.x; gv.y = g1 * sc * nw2.y;
      *(float2*)(&sZx[lt * 260 + k0]) = gv;
    }
    __syncthreads();
    // ---- 7. out-matmul: (m, k-eighth)/thread, shfl reduce (no barrier:
    //         next write to sZx is step 3', two barriers away) ----
    {
      #pragma unroll
      for (int lt = 0; lt < 8; ++lt) {
        const float4* gp = (const float4*)(&sZx[lt * 260 + (ke << 4)]);
        float pth = 0.f;
        #pragma unroll
        for (int i = 0; i < 4; ++i) {
          const float4 g4 = gp[i];
          pth += wcr[i * 4 + 0] * g4.x + wcr[i * 4 + 1] * g4.y +
                 wcr[i * 4 + 2] * g4.z + wcr[i * 4 + 3] * g4.w;
        }
        pth += __shfl_xor(pth, 1);
        pth += __shfl_xor(pth, 2);
        pth += __shfl_xor(pth, 4);
        if (ke == 0) {
          const int st = (ck << 3) + lt, rp = dir ? (127 - st) : st;
          ybuf[(((size_t)(dir * 512 + seq) * 128 + rp) << 6) + m_own] = f2bf(pth);
        }
      }
    }
  }
}

// ---------------------------------------------------------------------------
// combine0: x1[b][f][t][c] = x[b][c][t][f] + yf + yb + fb0[c]   (coalesced)
// ---------------------------------------------------------------------------
__global__ __launch_bounds__(256) void combine0(
    const float* __restrict__ x, const unsigned short* __restrict__ ybuf,
    const float* __restrict__ fb, float* __restrict__ x1)
{
  __shared__ float T[64 * 132];
  const int tid = threadIdx.x, blk = blockIdx.x;
  const int b = blk >> 7, t = blk & 127;
  {
    const int c = tid >> 2, f0 = (tid & 3) << 5;
    const float* xp = x + (((size_t)(b * 64 + c) * 128 + t) << 7) + f0;
    float* tp = &T[c * 132 + f0];
    #pragma unroll
    for (int j = 0; j < 8; ++j)
      *(float4*)(tp + (j << 2)) = *(const float4*)(xp + (j << 2));
  }
  __syncthreads();
  {
    const int f = tid >> 1, cb = (tid & 1) << 5;
    const size_t s0 = (size_t)b * 128 + t;
    const unsigned short* yf = ybuf + ((s0 * 128 + f) << 6) + cb;
    const unsigned short* yb = ybuf + (((s0 + 512) * 128 + f) << 6) + cb;
    float* op = x1 + (((size_t)(b * 128 + f) * 128 + t) << 6) + cb;
    #pragma unroll
    for (int j = 0; j < 32; j += 4) {
      float4 v;
      v.x = T[(cb + j + 0) * 132 + f] + bfu(yf[j + 0]) + bfu(yb[j + 0]) + fb[cb + j + 0];
      v.y = T[(cb + j + 1) * 132 + f] + bfu(yf[j + 1]) + bfu(yb[j + 1]) + fb[cb + j + 1];
      v.z = T[(cb + j + 2) * 132 + f] + bfu(yf[j + 2]) + bfu(yb[j + 2]) + fb[cb + j + 2];
      v.w = T[(cb + j + 3) * 132 + f] + bfu(yf[j + 3]) + bfu(yb[j + 3]) + fb[cb + j + 3];
      *(float4*)(op + j) = v;
    }
  }
}

// ---------------------------------------------------------------------------
// combine1: out[b][c][t][f] = x1[b][f][t][c] + yf + yb + fb1[c]  (coalesced)
// ---------------------------------------------------------------------------
__global__ __launch_bounds__(256) void combine1(
    const float* __restrict__ x1, const unsigned short* __restrict__ ybuf,
    const float* __restrict__ fb, float* __restrict__ out)
{
  __shared__ float T[128 * 68];
  const int tid = threadIdx.x, blk = blockIdx.x;
  const int b = blk >> 7, t = blk & 127;
  {
    const int f = tid >> 1, cb = (tid & 1) << 5;
    const size_t s1 = (size_t)b * 128 + f;
    const float* xp = x1 + ((s1 * 128 + t) << 6) + cb;
    const unsigned short* yf = ybuf + ((s1 * 128 + t) << 6) + cb;
    const unsigned short* yb = ybuf + (((s1 + 512) * 128 + t) << 6) + cb;
    float* tp = &T[f * 68 + cb];
    #pragma unroll
    for (int j = 0; j < 32; ++j)
      tp[j] = xp[j] + bfu(yf[j]) + bfu(yb[j]) + fb[cb + j];
  }
  __syncthreads();
  {
    const int c = tid >> 2, f0 = (tid & 3) << 5;
    float* op = out + (((size_t)(b * 64 + c) * 128 + t) << 7) + f0;
    #pragma unroll
    for (int j = 0; j < 32; j += 4) {
      float4 v;
      v.x = T[(f0 + j + 0) * 68 + c];
      v.y = T[(f0 + j + 1) * 68 + c];
      v.z = T[(f0 + j + 2) * 68 + c];
      v.w = T[(f0 + j + 3) * 68 + c];
      *(float4*)(op + j) = v;
    }
  }
}

extern "C" void kernel_launch(void* const* d_in, const int* in_sizes, int n_in,
                              void* d_out, int out_size, void* d_ws, size_t ws_size,
                              hipStream_t stream) {
  const float* x   = (const float*)d_in[0];
  const float* Wp  = (const float*)d_in[1];
  const float* cw  = (const float*)d_in[2];
  const float* cb  = (const float*)d_in[3];
  const float* dtb = (const float*)d_in[4];
  const float* Al  = (const float*)d_in[5];
  const float* Dp  = (const float*)d_in[6];
  const float* nw  = (const float*)d_in[7];
  const float* oW  = (const float*)d_in[8];
  const float* fW  = (const float*)d_in[9];
  const float* fb  = (const float*)d_in[10];
  const float* lnw = (const float*)d_in[11];
  const float* lnb = (const float*)d_in[12];

  float* ws = (float*)d_ws;
  float* Wc = ws;                                   // 32768 f32
  unsigned short* WpF = (unsigned short*)(ws + 32768); // 4*25600 bf16 = 51200 f32
  float* x1 = ws + 32768 + 51200;                   // 4194304 f32
  unsigned short* y = (unsigned short*)(x1 + 4194304); // 8388608 bf16

  precomp_wc<<<32, 256, 0, stream>>>(fW, oW, Wc);
  precomp_wpf<<<4, 256, 0, stream>>>(Wp, WpF);
  mamba_dir<<<1024, 512, 0, stream>>>(x, x1, y, WpF, cw, cb, dtb, Al, Dp,
                                      nw, lnw, lnb, Wc, 0);
  combine0<<<512, 256, 0, stream>>>(x, y, fb, x1);
  mamba_dir<<<1024, 512, 0, stream>>>(x, x1, y, WpF, cw, cb, dtb, Al, Dp,
                                      nw, lnw, lnb, Wc, 1);
  combine1<<<512, 256, 0, stream>>>(x1, y, fb + 64, (float*)d_out);
}

// Round 10
// 655.211 us; speedup vs baseline: 11.2773x; 1.0951x over previous
//
#include <hip/hip_runtime.h>

#define EPSV 1e-5f

typedef short bf16x8 __attribute__((ext_vector_type(8)));
typedef float f32x4 __attribute__((ext_vector_type(4)));

__device__ __forceinline__ float sigmoidf_(float x) {
  return 1.f / (1.f + __expf(-x));
}
__device__ __forceinline__ unsigned short f2bf(float f) {
  unsigned int u = __float_as_uint(f);
  u += 0x7fffu + ((u >> 16) & 1u);
  return (unsigned short)(u >> 16);
}
__device__ __forceinline__ float bfu(unsigned short h) {
  union { unsigned int u; float f; } t; t.u = ((unsigned int)h) << 16; return t.f;
}
__device__ __forceinline__ float bflo(unsigned int u) {
  union { unsigned int x; float f; } t; t.x = u << 16; return t.f;
}
__device__ __forceinline__ float bfhi(unsigned int u) {
  union { unsigned int x; float f; } t; t.x = u & 0xffff0000u; return t.f;
}

// ---------------------------------------------------------------------------
// W_comb[i][m][k] = sum_j fusion_W[p][m][d*64+j] * out_W[i][j][k]
// ---------------------------------------------------------------------------
__global__ __launch_bounds__(256) void precomp_wc(
    const float* __restrict__ fW,   // (2,64,128)
    const float* __restrict__ oW,   // (4,64,128)
    float* __restrict__ Wc)         // (4,64,128)
{
  const int bi = blockIdx.x;
  const int i = bi >> 3, mg = bi & 7;
  const int m = (mg << 3) + (threadIdx.x >> 5);
  const int k0 = (threadIdx.x & 31) << 2;
  const int p = i >> 1, d = i & 1;
  const float* fr = fW + p * 8192 + m * 128 + d * 64;
  const float* orow = oW + i * 8192 + k0;
  float a0 = 0.f, a1 = 0.f, a2 = 0.f, a3 = 0.f;
  for (int j = 0; j < 64; ++j) {
    const float f = fr[j];
    const float4 o4 = *(const float4*)(orow + j * 128);
    a0 += f * o4.x; a1 += f * o4.y; a2 += f * o4.z; a3 += f * o4.w;
  }
  float* out = Wc + i * 8192 + m * 128 + k0;
  out[0] = a0; out[1] = a1; out[2] = a2; out[3] = a3;
}

// ---------------------------------------------------------------------------
// in_proj weights -> bf16 in MFMA B-fragment order (1KB coalesced per wave).
// ---------------------------------------------------------------------------
__global__ __launch_bounds__(256) void precomp_wpf(
    const float* __restrict__ Wp, unsigned short* __restrict__ WpF)
{
  const int ip = blockIdx.x;
  const float* src = Wp + (size_t)ip * 24704;
  unsigned short* dst = WpF + (size_t)ip * 25600;
  for (int idx = threadIdx.x; idx < 25600; idx += 256) {
    const int tile = idx >> 10;
    const int rem = idx & 1023;
    const int h = rem >> 9;
    const int lane = (rem >> 3) & 63;
    const int j = idx & 7;
    const int col = lane & 15, quad = lane >> 4;
    const int o = tile * 16 + col;
    const int k = h * 32 + quad * 8 + j;
    dst[idx] = (o < 386) ? f2bf(src[o * 64 + k]) : (unsigned short)0;
  }
}

// ---------------------------------------------------------------------------
// transp0: x0[b][t][f][c] = x[b][c][t][f]  (phase-0 gets the same compact
// [seq][pos][c] layout combine0 gives phase 1; buffers alias).
// ---------------------------------------------------------------------------
__global__ __launch_bounds__(256) void transp0(
    const float* __restrict__ x, float* __restrict__ x0)
{
  __shared__ float T[64 * 132];
  const int tid = threadIdx.x, blk = blockIdx.x;
  const int b = blk >> 7, t = blk & 127;
  {
    const int c = tid >> 2, f0 = (tid & 3) << 5;
    const float* xp = x + (((size_t)(b * 64 + c) * 128 + t) << 7) + f0;
    float* tp = &T[c * 132 + f0];
    #pragma unroll
    for (int j = 0; j < 8; ++j)
      *(float4*)(tp + (j << 2)) = *(const float4*)(xp + (j << 2));
  }
  __syncthreads();
  {
    const int f = tid >> 1, cb = (tid & 1) << 5;
    float* op = x0 + (((size_t)(b * 128 + t) * 128 + f) << 6) + cb;
    #pragma unroll
    for (int j = 0; j < 32; j += 4) {
      float4 v;
      v.x = T[(cb + j + 0) * 132 + f];
      v.y = T[(cb + j + 1) * 132 + f];
      v.z = T[(cb + j + 2) * 132 + f];
      v.w = T[(cb + j + 3) * 132 + f];
      *(float4*)(op + j) = v;
    }
  }
}

// ---------------------------------------------------------------------------
// One block = one (sequence, direction). 1024 blocks x 512 threads.
// CH=16 (8 chunks): 5 barriers/chunk = 40/block (was 96). Loads are fully
// coalesced register loads with next-chunk prefetch; LN fused (wave-shfl).
// MFMA A-operand: all 16 rows valid. LDS ~41 KB.
// ---------------------------------------------------------------------------
__global__ __launch_bounds__(512, 4) void mamba_dir(
    const float* __restrict__ src,   // [seq][pos][c] f32 (x0 or x1)
    unsigned short* __restrict__ ybuf, // bf16 [dir][seq][pos][64]
    const unsigned short* __restrict__ WpF, // bf16 fragments (4,25600)
    const float* __restrict__ cwA, const float* __restrict__ cbA,
    const float* __restrict__ dtbA, const float* __restrict__ AlA,
    const float* __restrict__ DpA, const float* __restrict__ nwA,
    const float* __restrict__ lnwA, const float* __restrict__ lnbA,
    const float* __restrict__ WcA,
    int phase)
{
  __shared__ __align__(16) unsigned short sU[16 * 72];  // 2.25 KB LN'd u (A)
  __shared__ __align__(16) unsigned short sZb[16 * 136];// 4.25 KB z (bf16)
  __shared__ __align__(16) float sZx[16 * 260];         // 16.6 KB xBC / y / g
  __shared__ float sX[16][256];                         // 16 KB conv+silu out
  __shared__ float sDtRaw[16][2], sDtv[16][2], sDa[16][2];

  const int tid = threadIdx.x;
  const int blk = blockIdx.x;
  const int seq = blk >> 1, dir = blk & 1;
  const int ip = (phase << 1) + dir;
  const float dtb0 = dtbA[ip * 2], dtb1 = dtbA[ip * 2 + 1];
  const float nA0 = -__expf(AlA[ip * 2]), nA1 = -__expf(AlA[ip * 2 + 1]);
  const float Dp0 = DpA[ip * 2], Dp1 = DpA[ip * 2 + 1];
  const int c256 = tid & 255;                 // conv channel
  const int lh = tid >> 8;                    // conv lt-half
  const float4 cw4 = *(const float4*)(cwA + ip * 1024 + (c256 << 2));
  const float cbias = cbA[ip * 256 + c256];
  float ch0 = 0.f, ch1 = 0.f, ch2 = 0.f;      // conv carry (lh==0 only)
  float S[16];                                // scan state (quarter-row)
  #pragma unroll
  for (int i = 0; i < 16; ++i) S[i] = 0.f;

  // Wc into registers: thread owns (m_own = tid>>3, ke = tid&7) -> 16 floats
  const int m_own = tid >> 3, ke = tid & 7;
  float wcr[16];
  {
    const float4* wsrc =
        (const float4*)(WcA + (size_t)ip * 8192 + (m_own << 7) + (ke << 4));
    #pragma unroll
    for (int i = 0; i < 4; ++i) {
      const float4 v = wsrc[i];
      wcr[i * 4 + 0] = v.x; wcr[i * 4 + 1] = v.y;
      wcr[i * 4 + 2] = v.z; wcr[i * 4 + 3] = v.w;
    }
  }
  const unsigned short* wf = WpF + (size_t)ip * 25600;
  const size_t sb = (size_t)seq << 13;
  const int pos = tid >> 6, lc = tid & 63;    // load/LN mapping
  const int lnb_i = (phase << 6) + lc;
  const float lnw_v = lnwA[lnb_i], lnb_v = lnbA[lnb_i];

  // preload chunk 0 (2 floats/thread, coalesced)
  float vc0, vc1;
  {
    const int p0 = dir ? (127 - pos) : pos;
    const int p1 = dir ? (127 - (pos + 8)) : (pos + 8);
    vc0 = src[sb + (size_t)p0 * 64 + lc];
    vc1 = src[sb + (size_t)p1 * 64 + lc];
  }

  for (int ck = 0; ck < 8; ++ck) {
    // ---- prefetch next chunk ----
    float vn0 = 0.f, vn1 = 0.f;
    if (ck < 7) {
      const int st0 = ((ck + 1) << 4) + pos;
      const int p0 = dir ? (127 - st0) : st0;
      const int p1 = dir ? (127 - (st0 + 8)) : (st0 + 8);
      vn0 = src[sb + (size_t)p0 * 64 + lc];
      vn1 = src[sb + (size_t)p1 * 64 + lc];
    }
    // ---- 1+2. layernorm in registers (wave-shfl), write bf16 sU ----
    #pragma unroll
    for (int half = 0; half < 2; ++half) {
      const float v = half ? vc1 : vc0;
      float sm = v, s2 = v * v;
      sm += __shfl_xor(sm, 1);  s2 += __shfl_xor(s2, 1);
      sm += __shfl_xor(sm, 2);  s2 += __shfl_xor(s2, 2);
      sm += __shfl_xor(sm, 4);  s2 += __shfl_xor(s2, 4);
      sm += __shfl_xor(sm, 8);  s2 += __shfl_xor(s2, 8);
      sm += __shfl_xor(sm, 16); s2 += __shfl_xor(s2, 16);
      sm += __shfl_xor(sm, 32); s2 += __shfl_xor(s2, 32);
      const float mean = sm * (1.f / 64.f);
      const float inv = rsqrtf(s2 * (1.f / 64.f) - mean * mean + EPSV);
      sU[(pos + half * 8) * 72 + lc] = f2bf((v - mean) * inv * lnw_v + lnb_v);
    }
    __syncthreads();   // B1: sU ready; also guards sZx vs prior step-7 reads
    // ---- 3. in_proj via MFMA; B fragments streamed from global/L2 ----
    {
      const int wave = tid >> 6, lane = tid & 63;
      const int col = lane & 15, quad = lane >> 4;
      const bf16x8 a0 = *(const bf16x8*)(&sU[col * 72 + quad * 8]);
      const bf16x8 a1 = *(const bf16x8*)(&sU[col * 72 + quad * 8 + 32]);
      for (int tile = wave; tile < 25; tile += 8) {
        const unsigned short* wt = wf + (tile << 10) + (lane << 3);
        const bf16x8 b0 = *(const bf16x8*)(wt);
        const bf16x8 b1 = *(const bf16x8*)(wt + 512);
        f32x4 d = {0.f, 0.f, 0.f, 0.f};
        d = __builtin_amdgcn_mfma_f32_16x16x32_bf16(a0, b0, d, 0, 0, 0);
        d = __builtin_amdgcn_mfma_f32_16x16x32_bf16(a1, b1, d, 0, 0, 0);
        const int o = (tile << 4) + col;
        if (tile < 8) {               // z -> bf16 (rows quad*4+r, all valid)
          #pragma unroll
          for (int r = 0; r < 4; ++r)
            sZb[(quad * 4 + r) * 136 + o] = f2bf(d[r]);
        } else if (tile < 24) {       // xBC -> f32
          #pragma unroll
          for (int r = 0; r < 4; ++r)
            sZx[(quad * 4 + r) * 260 + (o - 128)] = d[r];
        } else if (col < 2) {         // dt raw (o = 384,385)
          #pragma unroll
          for (int r = 0; r < 4; ++r)
            sDtRaw[quad * 4 + r][col] = d[r];
        }
      }
    }
    __syncthreads();   // B2
    // ---- 4. conv(4,causal)+silu; lt 0-7 on lh=0 (reg carry), 8-15 on lh=1 ----
    {
      const int c = c256;
      float a0c, a1c, a2c;
      if (lh == 0) { a0c = ch0; a1c = ch1; a2c = ch2; }
      else {
        a0c = sZx[5 * 260 + c];
        a1c = sZx[6 * 260 + c];
        a2c = sZx[7 * 260 + c];
      }
      const int lt0 = lh << 3;
      #pragma unroll
      for (int l = 0; l < 8; ++l) {
        const int lt = lt0 + l;
        const float a3 = sZx[lt * 260 + c];
        const float acc = cbias + a0c * cw4.x + a1c * cw4.y + a2c * cw4.z + a3 * cw4.w;
        sX[lt][c] = acc * sigmoidf_(acc);
        a0c = a1c; a1c = a2c; a2c = a3;
      }
      if (lh == 0) {   // carry = raw xBC at lt 13,14,15
        ch0 = sZx[13 * 260 + c];
        ch1 = sZx[14 * 260 + c];
        ch2 = sZx[15 * 260 + c];
      }
      if (tid < 32) {
        const int lt = tid >> 1, hh = tid & 1;
        const float rawv = sDtRaw[lt][hh] + (hh ? dtb1 : dtb0);
        const float dtv = (rawv > 20.f) ? rawv : log1pf(__expf(rawv));
        sDtv[lt][hh] = dtv;
        sDa[lt][hh] = __expf(dtv * (hh ? nA1 : nA0));
      }
    }
    __syncthreads();   // B3
    // ---- 5. selective scan: 128 rows x 4 quarters, 16 states each ----
    {
      const int row = tid >> 2, quarter = tid & 3, hh = row >> 6;
      const int boff = 128 + (quarter << 4);
      #pragma unroll
      for (int lt = 0; lt < 16; ++lt) {
        const float dtv = sDtv[lt][hh];
        const float dA = sDa[lt][hh];
        const float dtx = dtv * sX[lt][row];
        const float4* Bp = (const float4*)(&sX[lt][boff]);
        const float4* Cp = (const float4*)(&sX[lt][boff + 64]);
        float yp = 0.f;
        #pragma unroll
        for (int i = 0; i < 4; ++i) {
          const float4 Bv = Bp[i], Cv = Cp[i];
          S[i * 4 + 0] = S[i * 4 + 0] * dA + dtx * Bv.x; yp += S[i * 4 + 0] * Cv.x;
          S[i * 4 + 1] = S[i * 4 + 1] * dA + dtx * Bv.y; yp += S[i * 4 + 1] * Cv.y;
          S[i * 4 + 2] = S[i * 4 + 2] * dA + dtx * Bv.z; yp += S[i * 4 + 2] * Cv.z;
          S[i * 4 + 3] = S[i * 4 + 3] * dA + dtx * Bv.w; yp += S[i * 4 + 3] * Cv.w;
        }
        yp += __shfl_xor(yp, 1);
        yp += __shfl_xor(yp, 2);
        if (quarter == 0) sZx[lt * 260 + row] = yp;   // y into dead xBC x-region
      }
    }
    __syncthreads();   // B4
    // ---- 6. gate with silu(z) + rmsnorm (wave w handles lt = w, w+8) ----
    {
      const int w = tid >> 6, kk = tid & 63, k0 = kk << 1;
      const float dp = (kk >= 32) ? Dp1 : Dp0;
      #pragma unroll
      for (int sub = 0; sub < 2; ++sub) {
        const int lt = w + (sub << 3);
        const float2 yv = *(const float2*)(&sZx[lt * 260 + k0]);
        const unsigned int zp = *(const unsigned int*)(&sZb[lt * 136 + k0]);
        const float z0 = bflo(zp), z1 = bfhi(zp);
        const float2 xv = *(const float2*)(&sX[lt][k0]);
        const float g0 = (yv.x + dp * xv.x) * (z0 * sigmoidf_(z0));
        const float g1 = (yv.y + dp * xv.y) * (z1 * sigmoidf_(z1));
        float ssq = g0 * g0 + g1 * g1;
        ssq += __shfl_xor(ssq, 1);
        ssq += __shfl_xor(ssq, 2);
        ssq += __shfl_xor(ssq, 4);
        ssq += __shfl_xor(ssq, 8);
        ssq += __shfl_xor(ssq, 16);
        ssq += __shfl_xor(ssq, 32);
        const float sc = rsqrtf(ssq * (1.f / 128.f) + EPSV);
        const float2 nw2 = *(const float2*)(nwA + ip * 128 + k0);
        float2 gv;
        gv.x = g0 * sc * nw2.x; gv.y = g1 * sc * nw2.y;
        *(float2*)(&sZx[lt * 260 + k0]) = gv;
      }
    }
    __syncthreads();   // B5
    // ---- 7. out-matmul: (m, k-eighth)/thread, shfl reduce; no barrier ----
    {
      #pragma unroll
      for (int lt = 0; lt < 16; ++lt) {
        const float4* gp = (const float4*)(&sZx[lt * 260 + (ke << 4)]);
        float pth = 0.f;
        #pragma unroll
        for (int i = 0; i < 4; ++i) {
          const float4 g4 = gp[i];
          pth += wcr[i * 4 + 0] * g4.x + wcr[i * 4 + 1] * g4.y +
                 wcr[i * 4 + 2] * g4.z + wcr[i * 4 + 3] * g4.w;
        }
        pth += __shfl_xor(pth, 1);
        pth += __shfl_xor(pth, 2);
        pth += __shfl_xor(pth, 4);
        if (ke == 0) {
          const int st = (ck << 4) + lt, rp = dir ? (127 - st) : st;
          ybuf[(((size_t)(dir * 512 + seq) * 128 + rp) << 6) + m_own] = f2bf(pth);
        }
      }
    }
    vc0 = vn0; vc1 = vn1;
  }
}

// ---------------------------------------------------------------------------
// combine0: x1[b][f][t][c] = x[b][c][t][f] + yf + yb + fb0[c]   (coalesced)
// ---------------------------------------------------------------------------
__global__ __launch_bounds__(256) void combine0(
    const float* __restrict__ x, const unsigned short* __restrict__ ybuf,
    const float* __restrict__ fb, float* __restrict__ x1)
{
  __shared__ float T[64 * 132];
  const int tid = threadIdx.x, blk = blockIdx.x;
  const int b = blk >> 7, t = blk & 127;
  {
    const int c = tid >> 2, f0 = (tid & 3) << 5;
    const float* xp = x + (((size_t)(b * 64 + c) * 128 + t) << 7) + f0;
    float* tp = &T[c * 132 + f0];
    #pragma unroll
    for (int j = 0; j < 8; ++j)
      *(float4*)(tp + (j << 2)) = *(const float4*)(xp + (j << 2));
  }
  __syncthreads();
  {
    const int f = tid >> 1, cb = (tid & 1) << 5;
    const size_t s0 = (size_t)b * 128 + t;
    const unsigned short* yf = ybuf + ((s0 * 128 + f) << 6) + cb;
    const unsigned short* yb = ybuf + (((s0 + 512) * 128 + f) << 6) + cb;
    float* op = x1 + (((size_t)(b * 128 + f) * 128 + t) << 6) + cb;
    #pragma unroll
    for (int j = 0; j < 32; j += 4) {
      float4 v;
      v.x = T[(cb + j + 0) * 132 + f] + bfu(yf[j + 0]) + bfu(yb[j + 0]) + fb[cb + j + 0];
      v.y = T[(cb + j + 1) * 132 + f] + bfu(yf[j + 1]) + bfu(yb[j + 1]) + fb[cb + j + 1];
      v.z = T[(cb + j + 2) * 132 + f] + bfu(yf[j + 2]) + bfu(yb[j + 2]) + fb[cb + j + 2];
      v.w = T[(cb + j + 3) * 132 + f] + bfu(yf[j + 3]) + bfu(yb[j + 3]) + fb[cb + j + 3];
      *(float4*)(op + j) = v;
    }
  }
}

// ---------------------------------------------------------------------------
// combine1: out[b][c][t][f] = x1[b][f][t][c] + yf + yb + fb1[c]  (coalesced)
// ---------------------------------------------------------------------------
__global__ __launch_bounds__(256) void combine1(
    const float* __restrict__ x1, const unsigned short* __restrict__ ybuf,
    const float* __restrict__ fb, float* __restrict__ out)
{
  __shared__ float T[128 * 68];
  const int tid = threadIdx.x, blk = blockIdx.x;
  const int b = blk >> 7, t = blk & 127;
  {
    const int f = tid >> 1, cb = (tid & 1) << 5;
    const size_t s1 = (size_t)b * 128 + f;
    const float* xp = x1 + ((s1 * 128 + t) << 6) + cb;
    const unsigned short* yf = ybuf + ((s1 * 128 + t) << 6) + cb;
    const unsigned short* yb = ybuf + (((s1 + 512) * 128 + t) << 6) + cb;
    float* tp = &T[f * 68 + cb];
    #pragma unroll
    for (int j = 0; j < 32; ++j)
      tp[j] = xp[j] + bfu(yf[j]) + bfu(yb[j]) + fb[cb + j];
  }
  __syncthreads();
  {
    const int c = tid >> 2, f0 = (tid & 3) << 5;
    float* op = out + (((size_t)(b * 64 + c) * 128 + t) << 7) + f0;
    #pragma unroll
    for (int j = 0; j < 32; j += 4) {
      float4 v;
      v.x = T[(f0 + j + 0) * 68 + c];
      v.y = T[(f0 + j + 1) * 68 + c];
      v.z = T[(f0 + j + 2) * 68 + c];
      v.w = T[(f0 + j + 3) * 68 + c];
      *(float4*)(op + j) = v;
    }
  }
}

extern "C" void kernel_launch(void* const* d_in, const int* in_sizes, int n_in,
                              void* d_out, int out_size, void* d_ws, size_t ws_size,
                              hipStream_t stream) {
  const float* x   = (const float*)d_in[0];
  const float* Wp  = (const float*)d_in[1];
  const float* cw  = (const float*)d_in[2];
  const float* cb  = (const float*)d_in[3];
  const float* dtb = (const float*)d_in[4];
  const float* Al  = (const float*)d_in[5];
  const float* Dp  = (const float*)d_in[6];
  const float* nw  = (const float*)d_in[7];
  const float* oW  = (const float*)d_in[8];
  const float* fW  = (const float*)d_in[9];
  const float* fb  = (const float*)d_in[10];
  const float* lnw = (const float*)d_in[11];
  const float* lnb = (const float*)d_in[12];

  float* ws = (float*)d_ws;
  float* Wc = ws;                                   // 32768 f32
  unsigned short* WpF = (unsigned short*)(ws + 32768); // 4*25600 bf16
  float* xbuf = ws + 32768 + 51200;                 // 4194304 f32 (x0 / x1 alias)
  unsigned short* y = (unsigned short*)(xbuf + 4194304); // 8388608 bf16

  precomp_wc<<<32, 256, 0, stream>>>(fW, oW, Wc);
  precomp_wpf<<<4, 256, 0, stream>>>(Wp, WpF);
  transp0<<<512, 256, 0, stream>>>(x, xbuf);
  mamba_dir<<<1024, 512, 0, stream>>>(xbuf, y, WpF, cw, cb, dtb, Al, Dp,
                                      nw, lnw, lnb, Wc, 0);
  combine0<<<512, 256, 0, stream>>>(x, y, fb, xbuf);
  mamba_dir<<<1024, 512, 0, stream>>>(xbuf, y, WpF, cw, cb, dtb, Al, Dp,
                                      nw, lnw, lnb, Wc, 1);
  combine1<<<512, 256, 0, stream>>>(xbuf, y, fb + 64, (float*)d_out);
}

// Round 11
// 507.923 us; speedup vs baseline: 14.5475x; 1.2900x over previous
//
#include <hip/hip_runtime.h>

#define EPSV 1e-5f

typedef short bf16x8 __attribute__((ext_vector_type(8)));
typedef float f32x4 __attribute__((ext_vector_type(4)));
typedef float f32x2 __attribute__((ext_vector_type(2)));

__device__ __forceinline__ float sigmoidf_(float x) {
  return 1.f / (1.f + __expf(-x));
}
__device__ __forceinline__ unsigned short f2bf(float f) {
  unsigned int u = __float_as_uint(f);
  u += 0x7fffu + ((u >> 16) & 1u);
  return (unsigned short)(u >> 16);
}
__device__ __forceinline__ float bfu(unsigned short h) {
  union { unsigned int u; float f; } t; t.u = ((unsigned int)h) << 16; return t.f;
}
__device__ __forceinline__ float bflo(unsigned int u) {
  union { unsigned int x; float f; } t; t.x = u << 16; return t.f;
}
__device__ __forceinline__ float bfhi(unsigned int u) {
  union { unsigned int x; float f; } t; t.x = u & 0xffff0000u; return t.f;
}

// ---------------------------------------------------------------------------
// W_comb[i][m][k] = sum_j fusion_W[p][m][d*64+j] * out_W[i][j][k]
// ---------------------------------------------------------------------------
__global__ __launch_bounds__(256) void precomp_wc(
    const float* __restrict__ fW,   // (2,64,128)
    const float* __restrict__ oW,   // (4,64,128)
    float* __restrict__ Wc)         // (4,64,128)
{
  const int bi = blockIdx.x;
  const int i = bi >> 3, mg = bi & 7;
  const int m = (mg << 3) + (threadIdx.x >> 5);
  const int k0 = (threadIdx.x & 31) << 2;
  const int p = i >> 1, d = i & 1;
  const float* fr = fW + p * 8192 + m * 128 + d * 64;
  const float* orow = oW + i * 8192 + k0;
  float a0 = 0.f, a1 = 0.f, a2 = 0.f, a3 = 0.f;
  for (int j = 0; j < 64; ++j) {
    const float f = fr[j];
    const float4 o4 = *(const float4*)(orow + j * 128);
    a0 += f * o4.x; a1 += f * o4.y; a2 += f * o4.z; a3 += f * o4.w;
  }
  float* out = Wc + i * 8192 + m * 128 + k0;
  out[0] = a0; out[1] = a1; out[2] = a2; out[3] = a3;
}

// ---------------------------------------------------------------------------
// Wc -> bf16 MFMA B-fragment order: WcF[ip][tile(4)][h(4)][lane(64)][8]
//   element j = Wc[ip][m = tile*16+col][k = h*32 + quad*8 + j]
// ---------------------------------------------------------------------------
__global__ __launch_bounds__(256) void precomp_wcf(
    const float* __restrict__ Wc, unsigned short* __restrict__ WcF)
{
  const int ip = blockIdx.x;
  const float* src = Wc + (size_t)ip * 8192;
  unsigned short* dst = WcF + (size_t)ip * 8192;
  for (int idx = threadIdx.x; idx < 8192; idx += 256) {
    const int tile = idx >> 11;
    const int h = (idx >> 9) & 3;
    const int lane = (idx >> 3) & 63;
    const int j = idx & 7;
    const int col = lane & 15, quad = lane >> 4;
    dst[idx] = f2bf(src[(tile * 16 + col) * 128 + h * 32 + quad * 8 + j]);
  }
}

// ---------------------------------------------------------------------------
// in_proj weights -> bf16 in MFMA B-fragment order (1KB coalesced per wave).
// ---------------------------------------------------------------------------
__global__ __launch_bounds__(256) void precomp_wpf(
    const float* __restrict__ Wp, unsigned short* __restrict__ WpF)
{
  const int ip = blockIdx.x;
  const float* src = Wp + (size_t)ip * 24704;
  unsigned short* dst = WpF + (size_t)ip * 25600;
  for (int idx = threadIdx.x; idx < 25600; idx += 256) {
    const int tile = idx >> 10;
    const int rem = idx & 1023;
    const int h = rem >> 9;
    const int lane = (rem >> 3) & 63;
    const int j = idx & 7;
    const int col = lane & 15, quad = lane >> 4;
    const int o = tile * 16 + col;
    const int k = h * 32 + quad * 8 + j;
    dst[idx] = (o < 386) ? f2bf(src[o * 64 + k]) : (unsigned short)0;
  }
}

// ---------------------------------------------------------------------------
// transp0: x0[b][t][f][c] = x[b][c][t][f]
// ---------------------------------------------------------------------------
__global__ __launch_bounds__(256) void transp0(
    const float* __restrict__ x, float* __restrict__ x0)
{
  __shared__ float T[64 * 132];
  const int tid = threadIdx.x, blk = blockIdx.x;
  const int b = blk >> 7, t = blk & 127;
  {
    const int c = tid >> 2, f0 = (tid & 3) << 5;
    const float* xp = x + (((size_t)(b * 64 + c) * 128 + t) << 7) + f0;
    float* tp = &T[c * 132 + f0];
    #pragma unroll
    for (int j = 0; j < 8; ++j)
      *(float4*)(tp + (j << 2)) = *(const float4*)(xp + (j << 2));
  }
  __syncthreads();
  {
    const int f = tid >> 1, cb = (tid & 1) << 5;
    float* op = x0 + (((size_t)(b * 128 + t) * 128 + f) << 6) + cb;
    #pragma unroll
    for (int j = 0; j < 32; j += 4) {
      float4 v;
      v.x = T[(cb + j + 0) * 132 + f];
      v.y = T[(cb + j + 1) * 132 + f];
      v.z = T[(cb + j + 2) * 132 + f];
      v.w = T[(cb + j + 3) * 132 + f];
      *(float4*)(op + j) = v;
    }
  }
}

// ---------------------------------------------------------------------------
// One block = one (sequence, direction). 1024 blocks x 512 threads, CH=16.
// in_proj AND out_proj via MFMA (B fragments from global/L2); scan in packed
// f32x2 (v_pk_fma_f32). 5 barriers/chunk. LDS ~40 KB.
// ---------------------------------------------------------------------------
__global__ __launch_bounds__(512, 4) void mamba_dir(
    const float* __restrict__ src,   // [seq][pos][c] f32 (x0 or x1)
    unsigned short* __restrict__ ybuf, // bf16 [dir][seq][pos][64]
    const unsigned short* __restrict__ WpF, // bf16 fragments (4,25600)
    const unsigned short* __restrict__ WcF, // bf16 fragments (4,8192)
    const float* __restrict__ cwA, const float* __restrict__ cbA,
    const float* __restrict__ dtbA, const float* __restrict__ AlA,
    const float* __restrict__ DpA, const float* __restrict__ nwA,
    const float* __restrict__ lnwA, const float* __restrict__ lnbA,
    int phase)
{
  __shared__ __align__(16) unsigned short sU[16 * 72];  // 2.25 KB LN'd u (A)
  __shared__ __align__(16) unsigned short sZb[16 * 136];// 4.25 KB z, then g (A)
  __shared__ __align__(16) float sZx[16 * 260];         // 16.6 KB xBC / y
  __shared__ float sX[16][256];                         // 16 KB conv+silu out
  __shared__ float sDtRaw[16][2], sDtv[16][2], sDa[16][2];

  const int tid = threadIdx.x;
  const int blk = blockIdx.x;
  const int seq = blk >> 1, dir = blk & 1;
  const int ip = (phase << 1) + dir;
  const float dtb0 = dtbA[ip * 2], dtb1 = dtbA[ip * 2 + 1];
  const float nA0 = -__expf(AlA[ip * 2]), nA1 = -__expf(AlA[ip * 2 + 1]);
  const float Dp0 = DpA[ip * 2], Dp1 = DpA[ip * 2 + 1];
  const int c256 = tid & 255;                 // conv channel
  const int lh = tid >> 8;                    // conv lt-half
  const float4 cw4 = *(const float4*)(cwA + ip * 1024 + (c256 << 2));
  const float cbias = cbA[ip * 256 + c256];
  float ch0 = 0.f, ch1 = 0.f, ch2 = 0.f;      // conv carry (lh==0 only)
  f32x2 S2[8];                                // scan state (packed pairs)
  #pragma unroll
  for (int i = 0; i < 8; ++i) S2[i] = (f32x2){0.f, 0.f};

  const unsigned short* wf = WpF + (size_t)ip * 25600;
  const unsigned short* wcf = WcF + (size_t)ip * 8192;
  const size_t sb = (size_t)seq << 13;
  const int pos = tid >> 6, lc = tid & 63;    // load/LN mapping
  const int lnb_i = (phase << 6) + lc;
  const float lnw_v = lnwA[lnb_i], lnb_v = lnbA[lnb_i];

  // preload chunk 0 (2 floats/thread, coalesced)
  float vc0, vc1;
  {
    const int p0 = dir ? (127 - pos) : pos;
    const int p1 = dir ? (127 - (pos + 8)) : (pos + 8);
    vc0 = src[sb + (size_t)p0 * 64 + lc];
    vc1 = src[sb + (size_t)p1 * 64 + lc];
  }

  for (int ck = 0; ck < 8; ++ck) {
    // ---- prefetch next chunk ----
    float vn0 = 0.f, vn1 = 0.f;
    if (ck < 7) {
      const int st0 = ((ck + 1) << 4) + pos;
      const int p0 = dir ? (127 - st0) : st0;
      const int p1 = dir ? (127 - (st0 + 8)) : (st0 + 8);
      vn0 = src[sb + (size_t)p0 * 64 + lc];
      vn1 = src[sb + (size_t)p1 * 64 + lc];
    }
    // ---- 1+2. layernorm in registers (wave-shfl), write bf16 sU ----
    #pragma unroll
    for (int half = 0; half < 2; ++half) {
      const float v = half ? vc1 : vc0;
      float sm = v, s2 = v * v;
      sm += __shfl_xor(sm, 1);  s2 += __shfl_xor(s2, 1);
      sm += __shfl_xor(sm, 2);  s2 += __shfl_xor(s2, 2);
      sm += __shfl_xor(sm, 4);  s2 += __shfl_xor(s2, 4);
      sm += __shfl_xor(sm, 8);  s2 += __shfl_xor(s2, 8);
      sm += __shfl_xor(sm, 16); s2 += __shfl_xor(s2, 16);
      sm += __shfl_xor(sm, 32); s2 += __shfl_xor(s2, 32);
      const float mean = sm * (1.f / 64.f);
      const float inv = rsqrtf(s2 * (1.f / 64.f) - mean * mean + EPSV);
      sU[(pos + half * 8) * 72 + lc] = f2bf((v - mean) * inv * lnw_v + lnb_v);
    }
    __syncthreads();   // B1: sU ready; guards sZb/sZx vs prior step-7/3 reads
    // ---- 3. in_proj via MFMA; B fragments streamed from global/L2 ----
    {
      const int wave = tid >> 6, lane = tid & 63;
      const int col = lane & 15, quad = lane >> 4;
      const bf16x8 a0 = *(const bf16x8*)(&sU[col * 72 + quad * 8]);
      const bf16x8 a1 = *(const bf16x8*)(&sU[col * 72 + quad * 8 + 32]);
      for (int tile = wave; tile < 25; tile += 8) {
        const unsigned short* wt = wf + (tile << 10) + (lane << 3);
        const bf16x8 b0 = *(const bf16x8*)(wt);
        const bf16x8 b1 = *(const bf16x8*)(wt + 512);
        f32x4 d = {0.f, 0.f, 0.f, 0.f};
        d = __builtin_amdgcn_mfma_f32_16x16x32_bf16(a0, b0, d, 0, 0, 0);
        d = __builtin_amdgcn_mfma_f32_16x16x32_bf16(a1, b1, d, 0, 0, 0);
        const int o = (tile << 4) + col;
        if (tile < 8) {               // z -> bf16
          #pragma unroll
          for (int r = 0; r < 4; ++r)
            sZb[(quad * 4 + r) * 136 + o] = f2bf(d[r]);
        } else if (tile < 24) {       // xBC -> f32
          #pragma unroll
          for (int r = 0; r < 4; ++r)
            sZx[(quad * 4 + r) * 260 + (o - 128)] = d[r];
        } else if (col < 2) {         // dt raw (o = 384,385)
          #pragma unroll
          for (int r = 0; r < 4; ++r)
            sDtRaw[quad * 4 + r][col] = d[r];
        }
      }
    }
    __syncthreads();   // B2
    // ---- 4. conv(4,causal)+silu; lt 0-7 on lh=0 (reg carry), 8-15 on lh=1 ----
    {
      const int c = c256;
      float a0c, a1c, a2c;
      if (lh == 0) { a0c = ch0; a1c = ch1; a2c = ch2; }
      else {
        a0c = sZx[5 * 260 + c];
        a1c = sZx[6 * 260 + c];
        a2c = sZx[7 * 260 + c];
      }
      const int lt0 = lh << 3;
      #pragma unroll
      for (int l = 0; l < 8; ++l) {
        const int lt = lt0 + l;
        const float a3 = sZx[lt * 260 + c];
        const float acc = cbias + a0c * cw4.x + a1c * cw4.y + a2c * cw4.z + a3 * cw4.w;
        sX[lt][c] = acc * sigmoidf_(acc);
        a0c = a1c; a1c = a2c; a2c = a3;
      }
      if (lh == 0) {   // carry = raw xBC at lt 13,14,15
        ch0 = sZx[13 * 260 + c];
        ch1 = sZx[14 * 260 + c];
        ch2 = sZx[15 * 260 + c];
      }
      if (tid < 32) {
        const int lt = tid >> 1, hh = tid & 1;
        const float rawv = sDtRaw[lt][hh] + (hh ? dtb1 : dtb0);
        const float dtv = (rawv > 20.f) ? rawv : log1pf(__expf(rawv));
        sDtv[lt][hh] = dtv;
        sDa[lt][hh] = __expf(dtv * (hh ? nA1 : nA0));
      }
    }
    __syncthreads();   // B3
    // ---- 5. selective scan: packed f32x2 (v_pk_fma_f32) ----
    {
      const int row = tid >> 2, quarter = tid & 3, hh = row >> 6;
      const int boff = 128 + (quarter << 4);
      #pragma unroll
      for (int lt = 0; lt < 16; ++lt) {
        const float dtv = sDtv[lt][hh];
        const float dA = sDa[lt][hh];
        const float dtx = dtv * sX[lt][row];
        const f32x2 dA2 = {dA, dA};
        const f32x2 dtx2 = {dtx, dtx};
        const float4* Bp = (const float4*)(&sX[lt][boff]);
        const float4* Cp = (const float4*)(&sX[lt][boff + 64]);
        f32x2 yp2 = {0.f, 0.f};
        #pragma unroll
        for (int i = 0; i < 4; ++i) {
          const float4 Bv = Bp[i], Cv = Cp[i];
          const f32x2 b0 = {Bv.x, Bv.y}, b1 = {Bv.z, Bv.w};
          const f32x2 c0 = {Cv.x, Cv.y}, c1 = {Cv.z, Cv.w};
          S2[i * 2]     = S2[i * 2]     * dA2 + dtx2 * b0;
          yp2 += S2[i * 2] * c0;
          S2[i * 2 + 1] = S2[i * 2 + 1] * dA2 + dtx2 * b1;
          yp2 += S2[i * 2 + 1] * c1;
        }
        float yp = yp2.x + yp2.y;
        yp += __shfl_xor(yp, 1);
        yp += __shfl_xor(yp, 2);
        if (quarter == 0) sZx[lt * 260 + row] = yp;   // y into dead xBC x-region
      }
    }
    __syncthreads();   // B4
    // ---- 6. gate with silu(z) + rmsnorm -> bf16 g IN PLACE over z (sZb) ----
    {
      const int w = tid >> 6, kk = tid & 63, k0 = kk << 1;
      const float dp = (kk >= 32) ? Dp1 : Dp0;
      #pragma unroll
      for (int sub = 0; sub < 2; ++sub) {
        const int lt = w + (sub << 3);
        const float2 yv = *(const float2*)(&sZx[lt * 260 + k0]);
        const unsigned int zp = *(const unsigned int*)(&sZb[lt * 136 + k0]);
        const float z0 = bflo(zp), z1 = bfhi(zp);
        const float2 xv = *(const float2*)(&sX[lt][k0]);
        const float g0 = (yv.x + dp * xv.x) * (z0 * sigmoidf_(z0));
        const float g1 = (yv.y + dp * xv.y) * (z1 * sigmoidf_(z1));
        float ssq = g0 * g0 + g1 * g1;
        ssq += __shfl_xor(ssq, 1);
        ssq += __shfl_xor(ssq, 2);
        ssq += __shfl_xor(ssq, 4);
        ssq += __shfl_xor(ssq, 8);
        ssq += __shfl_xor(ssq, 16);
        ssq += __shfl_xor(ssq, 32);
        const float sc = rsqrtf(ssq * (1.f / 128.f) + EPSV);
        const float2 nw2 = *(const float2*)(nwA + ip * 128 + k0);
        const unsigned int lo = f2bf(g0 * sc * nw2.x);
        const unsigned int hi = f2bf(g1 * sc * nw2.y);
        *(unsigned int*)(&sZb[lt * 136 + k0]) = lo | (hi << 16);
      }
    }
    __syncthreads();   // B5
    // ---- 7. out-matmul via MFMA: g (16x128, A=sZb rows) @ WcF (4 m-tiles) ----
    {
      const int wave = tid >> 6, lane = tid & 63;
      if (wave < 4) {
        const int col = lane & 15, quad = lane >> 4;
        const unsigned short* wt = wcf + (wave << 11);
        f32x4 d = {0.f, 0.f, 0.f, 0.f};
        #pragma unroll
        for (int h = 0; h < 4; ++h) {
          const bf16x8 a = *(const bf16x8*)(&sZb[col * 136 + (h << 5) + (quad << 3)]);
          const bf16x8 bb = *(const bf16x8*)(wt + (h << 9) + (lane << 3));
          d = __builtin_amdgcn_mfma_f32_16x16x32_bf16(a, bb, d, 0, 0, 0);
        }
        const size_t yb = ((size_t)(dir * 512 + seq) * 128) << 6;
        #pragma unroll
        for (int r = 0; r < 4; ++r) {
          const int pp = (quad << 2) + r;
          const int st = (ck << 4) + pp, rp = dir ? (127 - st) : st;
          ybuf[yb + ((size_t)rp << 6) + (wave << 4) + col] = f2bf(d[r]);
        }
      }
    }
    vc0 = vn0; vc1 = vn1;
  }
}

// ---------------------------------------------------------------------------
// combine0: x1[b][f][t][c] = x[b][c][t][f] + yf + yb + fb0[c]   (coalesced)
// ---------------------------------------------------------------------------
__global__ __launch_bounds__(256) void combine0(
    const float* __restrict__ x, const unsigned short* __restrict__ ybuf,
    const float* __restrict__ fb, float* __restrict__ x1)
{
  __shared__ float T[64 * 132];
  const int tid = threadIdx.x, blk = blockIdx.x;
  const int b = blk >> 7, t = blk & 127;
  {
    const int c = tid >> 2, f0 = (tid & 3) << 5;
    const float* xp = x + (((size_t)(b * 64 + c) * 128 + t) << 7) + f0;
    float* tp = &T[c * 132 + f0];
    #pragma unroll
    for (int j = 0; j < 8; ++j)
      *(float4*)(tp + (j << 2)) = *(const float4*)(xp + (j << 2));
  }
  __syncthreads();
  {
    const int f = tid >> 1, cb = (tid & 1) << 5;
    const size_t s0 = (size_t)b * 128 + t;
    const unsigned short* yf = ybuf + ((s0 * 128 + f) << 6) + cb;
    const unsigned short* yb = ybuf + (((s0 + 512) * 128 + f) << 6) + cb;
    float* op = x1 + (((size_t)(b * 128 + f) * 128 + t) << 6) + cb;
    #pragma unroll
    for (int j = 0; j < 32; j += 4) {
      float4 v;
      v.x = T[(cb + j + 0) * 132 + f] + bfu(yf[j + 0]) + bfu(yb[j + 0]) + fb[cb + j + 0];
      v.y = T[(cb + j + 1) * 132 + f] + bfu(yf[j + 1]) + bfu(yb[j + 1]) + fb[cb + j + 1];
      v.z = T[(cb + j + 2) * 132 + f] + bfu(yf[j + 2]) + bfu(yb[j + 2]) + fb[cb + j + 2];
      v.w = T[(cb + j + 3) * 132 + f] + bfu(yf[j + 3]) + bfu(yb[j + 3]) + fb[cb + j + 3];
      *(float4*)(op + j) = v;
    }
  }
}

// ---------------------------------------------------------------------------
// combine1: out[b][c][t][f] = x1[b][f][t][c] + yf + yb + fb1[c]  (coalesced)
// ---------------------------------------------------------------------------
__global__ __launch_bounds__(256) void combine1(
    const float* __restrict__ x1, const unsigned short* __restrict__ ybuf,
    const float* __restrict__ fb, float* __restrict__ out)
{
  __shared__ float T[128 * 68];
  const int tid = threadIdx.x, blk = blockIdx.x;
  const int b = blk >> 7, t = blk & 127;
  {
    const int f = tid >> 1, cb = (tid & 1) << 5;
    const size_t s1 = (size_t)b * 128 + f;
    const float* xp = x1 + ((s1 * 128 + t) << 6) + cb;
    const unsigned short* yf = ybuf + ((s1 * 128 + t) << 6) + cb;
    const unsigned short* yb = ybuf + (((s1 + 512) * 128 + t) << 6) + cb;
    float* tp = &T[f * 68 + cb];
    #pragma unroll
    for (int j = 0; j < 32; ++j)
      tp[j] = xp[j] + bfu(yf[j]) + bfu(yb[j]) + fb[cb + j];
  }
  __syncthreads();
  {
    const int c = tid >> 2, f0 = (tid & 3) << 5;
    float* op = out + (((size_t)(b * 64 + c) * 128 + t) << 7) + f0;
    #pragma unroll
    for (int j = 0; j < 32; j += 4) {
      float4 v;
      v.x = T[(f0 + j + 0) * 68 + c];
      v.y = T[(f0 + j + 1) * 68 + c];
      v.z = T[(f0 + j + 2) * 68 + c];
      v.w = T[(f0 + j + 3) * 68 + c];
      *(float4*)(op + j) = v;
    }
  }
}

extern "C" void kernel_launch(void* const* d_in, const int* in_sizes, int n_in,
                              void* d_out, int out_size, void* d_ws, size_t ws_size,
                              hipStream_t stream) {
  const float* x   = (const float*)d_in[0];
  const float* Wp  = (const float*)d_in[1];
  const float* cw  = (const float*)d_in[2];
  const float* cb  = (const float*)d_in[3];
  const float* dtb = (const float*)d_in[4];
  const float* Al  = (const float*)d_in[5];
  const float* Dp  = (const float*)d_in[6];
  const float* nw  = (const float*)d_in[7];
  const float* oW  = (const float*)d_in[8];
  const float* fW  = (const float*)d_in[9];
  const float* fb  = (const float*)d_in[10];
  const float* lnw = (const float*)d_in[11];
  const float* lnb = (const float*)d_in[12];

  float* ws = (float*)d_ws;
  float* Wc = ws;                                       // 32768 f32
  unsigned short* WpF = (unsigned short*)(ws + 32768);  // 102400 shorts
  unsigned short* WcF = (unsigned short*)(ws + 32768 + 51200); // 32768 shorts
  float* xbuf = ws + 32768 + 51200 + 16384;             // 4194304 f32
  unsigned short* y = (unsigned short*)(xbuf + 4194304); // 8388608 bf16

  precomp_wc<<<32, 256, 0, stream>>>(fW, oW, Wc);
  precomp_wcf<<<4, 256, 0, stream>>>(Wc, WcF);
  precomp_wpf<<<4, 256, 0, stream>>>(Wp, WpF);
  transp0<<<512, 256, 0, stream>>>(x, xbuf);
  mamba_dir<<<1024, 512, 0, stream>>>(xbuf, y, WpF, WcF, cw, cb, dtb, Al, Dp,
                                      nw, lnw, lnb, 0);
  combine0<<<512, 256, 0, stream>>>(x, y, fb, xbuf);
  mamba_dir<<<1024, 512, 0, stream>>>(xbuf, y, WpF, WcF, cw, cb, dtb, Al, Dp,
                                      nw, lnw, lnb, 1);
  combine1<<<512, 256, 0, stream>>>(xbuf, y, fb + 64, (float*)d_out);
}